// Round 1
// baseline (464.725 us; speedup 1.0000x reference)
//
#include <hip/hip_runtime.h>
#include <cstdint>
#include <cstddef>

#define NA 8400   // anchors per image: 80*80 + 40*40 + 20*20
#define NB 32     // batch
#define NG 20     // ground truths per image
#define NCL 80    // classes

// ---------- device helpers ----------

__device__ __forceinline__ const float* anchor_base(const float* p8, const float* p16,
                                                    const float* p32, int b, int a,
                                                    int& hw, int& HW) {
  if (a < 6400)      { hw = a;        HW = 6400; return p8  + (size_t)b * 85 * 6400; }
  else if (a < 8000) { hw = a - 6400; HW = 1600; return p16 + (size_t)b * 85 * 1600; }
  hw = a - 8000; HW = 400; return p32 + (size_t)b * 85 * 400;
}

__device__ __forceinline__ float iou_raw(float gx, float gy, float gw, float gh, float4 p) {
  float gtlx = gx - gw * 0.5f, gtly = gy - gh * 0.5f;
  float gbrx = gx + gw * 0.5f, gbry = gy + gh * 0.5f;
  float ptlx = p.x - p.z * 0.5f, ptly = p.y - p.w * 0.5f;
  float pbrx = p.x + p.z * 0.5f, pbry = p.y + p.w * 0.5f;
  float tlx = fmaxf(gtlx, ptlx), tly = fmaxf(gtly, ptly);
  float brx = fminf(gbrx, pbrx), bry = fminf(gbry, pbry);
  float inter = ((tlx < brx) && (tly < bry)) ? (brx - tlx) * (bry - tly) : 0.0f;
  float ag = gw * gh, ap = p.z * p.w;
  return inter / (ag + ap - inter + 1e-16f);
}

// Reference cost: cls_cost + 3*iou_cost + 1e5*(!in_both) + 1e9*(!fg_cand)
// cls_cost = -((lp - l1p)[class] + sum_l1p); p = sqrt(sig(cls)*sig(obj))
__device__ __forceinline__ float cost_fn(float x, float sig_obj_v, float sum_l1p_v,
                                         float ioum, bool fg, bool ib) {
  float sc  = 1.0f / (1.0f + expf(-x));
  float p   = sqrtf(sc * sig_obj_v);
  float lp  = fmaxf(logf(p), -100.0f);
  float l1p = fmaxf(log1pf(-p), -100.0f);
  float cls_cost = -((lp - l1p) + sum_l1p_v);
  float iou_cost = -logf(ioum + 1e-8f);
  float c = cls_cost + 3.0f * iou_cost;
  if (!ib) c += 100000.0f;
  if (!fg) c += 1000000000.0f;
  return c;
}

__device__ __forceinline__ float giou_loss(float4 bb, float gx, float gy, float gw, float gh) {
  float btlx = bb.x - bb.z * 0.5f, btly = bb.y - bb.w * 0.5f;
  float bbrx = bb.x + bb.z * 0.5f, bbry = bb.y + bb.w * 0.5f;
  float gtlx = gx - gw * 0.5f, gtly = gy - gh * 0.5f;
  float gbrx = gx + gw * 0.5f, gbry = gy + gh * 0.5f;
  float tlx = fmaxf(btlx, gtlx), tly = fmaxf(btly, gtly);
  float brx = fminf(bbrx, gbrx), bry = fminf(bbry, gbry);
  float area_b = bb.z * bb.w, area_g = gw * gh;
  float inter = ((tlx < brx) && (tly < bry)) ? (brx - tlx) * (bry - tly) : 0.0f;
  float uni = area_b + area_g - inter;
  float iou = inter / (uni + 1e-16f);
  float ctlx = fminf(btlx, gtlx), ctly = fminf(btly, gtly);
  float cbrx = fmaxf(bbrx, gbrx), cbry = fmaxf(bbry, gbry);
  float area_c = fmaxf((cbrx - ctlx) * (cbry - ctly), 1e-16f);
  float giou = iou - (area_c - uni) / area_c;
  giou = fminf(fmaxf(giou, -1.0f), 1.0f);
  return 1.0f - giou;
}

// ---------- kernel A: decode + per-anchor precompute ----------
// accum layout: [0]=loss_iou [1]=loss_obj_base [2]=obj_extra(sum obj logit over fg)
//               [3]=loss_cls [4]=num_fg
__global__ __launch_bounds__(256) void kA(const float* __restrict__ p8,
                                          const float* __restrict__ p16,
                                          const float* __restrict__ p32,
                                          const float* __restrict__ labels,
                                          float4* __restrict__ bbox,
                                          float* __restrict__ sig_obj,
                                          float* __restrict__ sum_l1p,
                                          float* __restrict__ sum_bce0,
                                          unsigned int* __restrict__ amask,
                                          float* __restrict__ accum) {
  __shared__ float s_gt[NG * 5];
  __shared__ float s_red[256];
  int b = blockIdx.y;
  int tid = threadIdx.x;
  if (tid < NG * 5) s_gt[tid] = labels[(size_t)b * NG * 5 + tid];
  __syncthreads();

  int a = blockIdx.x * 256 + tid;
  float bce_obj = 0.0f;
  if (a < NA) {
    int hw, HW, W, stride;
    const float* base;
    if (a < 6400)      { hw = a;        HW = 6400; W = 80; stride = 8;  base = p8  + (size_t)b * 85 * 6400; }
    else if (a < 8000) { hw = a - 6400; HW = 1600; W = 40; stride = 16; base = p16 + (size_t)b * 85 * 1600; }
    else               { hw = a - 8000; HW = 400;  W = 20; stride = 32; base = p32 + (size_t)b * 85 * 400;  }
    int xg = hw % W, yg = hw / W;
    float fs = (float)stride;

    float v0 = base[hw];
    float v1 = base[HW + hw];
    float v2 = base[2 * HW + hw];
    float v3 = base[3 * HW + hw];
    float obj = base[4 * HW + hw];

    float bx = (v0 + (float)xg) * fs;
    float by = (v1 + (float)yg) * fs;
    float bw = expf(v2) * fs;
    float bh = expf(v3) * fs;
    bbox[(size_t)b * NA + a] = make_float4(bx, by, bw, bh);

    float so = 1.0f / (1.0f + expf(-obj));
    sig_obj[(size_t)b * NA + a] = so;
    bce_obj = fmaxf(obj, 0.0f) + log1pf(expf(-fabsf(obj)));

    float sl = 0.0f, sb = 0.0f;
    for (int c = 0; c < NCL; ++c) {
      float x  = base[(5 + c) * HW + hw];
      float sc = 1.0f / (1.0f + expf(-x));
      float p  = sqrtf(sc * so);
      sl += fmaxf(log1pf(-p), -100.0f);
      sb += fmaxf(x, 0.0f) + log1pf(expf(-fabsf(x)));
    }
    sum_l1p[(size_t)b * NA + a]  = sl;
    sum_bce0[(size_t)b * NA + a] = sb;

    // geometric candidate masks
    float xc = ((float)xg + 0.5f) * fs;
    float yc = ((float)yg + 0.5f) * fs;
    float r = 2.5f * fs;
    unsigned int msk = 0u;
    bool fg = false;
    for (int g = 0; g < NG; ++g) {
      float gx = s_gt[g * 5 + 0], gy = s_gt[g * 5 + 1];
      float gw = s_gt[g * 5 + 2], gh = s_gt[g * 5 + 3];
      bool inb = (xc > gx - 0.5f * gw) && (xc < gx + 0.5f * gw) &&
                 (yc > gy - 0.5f * gh) && (yc < gy + 0.5f * gh);
      bool inc = (xc > gx - r) && (xc < gx + r) && (yc > gy - r) && (yc < gy + r);
      fg = fg || inb || inc;
      if (inb && inc) msk |= (1u << g);
    }
    if (fg) msk |= 0x80000000u;
    amask[(size_t)b * NA + a] = msk;
  }

  // block-reduce loss_obj base term (bce(obj,0) over ALL anchors)
  s_red[tid] = bce_obj;
  __syncthreads();
  for (int s = 128; s > 0; s >>= 1) {
    if (tid < s) s_red[tid] += s_red[tid + s];
    __syncthreads();
  }
  if (tid == 0) atomicAdd(&accum[1], s_red[0]);
}

// ---------- kernel B: per (b,g) cost row + dyn_k top-k selection ----------
__global__ __launch_bounds__(256) void kB(const float* __restrict__ p8,
                                          const float* __restrict__ p16,
                                          const float* __restrict__ p32,
                                          const float* __restrict__ labels,
                                          const float4* __restrict__ bbox,
                                          const float* __restrict__ sig_obj,
                                          const float* __restrict__ sum_l1p,
                                          const unsigned int* __restrict__ amask,
                                          unsigned int* __restrict__ match_mask) {
  __shared__ float s_cost[NA];        // 33.6 KB
  __shared__ float s_top[256 * 10];   // 10.2 KB
  __shared__ float s_rv[256];
  __shared__ int   s_ri[256];
  __shared__ int   s_k;

  int g = blockIdx.x, b = blockIdx.y, tid = threadIdx.x;
  size_t bA = (size_t)b * NA;

  float gx = labels[(size_t)b * NG * 5 + g * 5 + 0];
  float gy = labels[(size_t)b * NG * 5 + g * 5 + 1];
  float gw = labels[(size_t)b * NG * 5 + g * 5 + 2];
  float gh = labels[(size_t)b * NG * 5 + g * 5 + 3];
  int   cg = (int)labels[(size_t)b * NG * 5 + g * 5 + 4];

  float t10[10];
#pragma unroll
  for (int j = 0; j < 10; ++j) t10[j] = 0.0f;

  for (int a = tid; a < NA; a += 256) {
    float4 pb = bbox[bA + a];
    float iou = iou_raw(gx, gy, gw, gh, pb);
    unsigned int am = amask[bA + a];
    bool fg = (am & 0x80000000u) != 0u;
    bool ib = ((am >> g) & 1u) != 0u;
    float ioum = fg ? iou : 0.0f;

    // maintain per-thread top-10 of masked ious (descending)
    if (ioum > t10[9]) {
      t10[9] = ioum;
#pragma unroll
      for (int j = 9; j > 0; --j) {
        if (t10[j] > t10[j - 1]) { float t = t10[j]; t10[j] = t10[j - 1]; t10[j - 1] = t; }
        else break;
      }
    }

    int hw, HW;
    const float* base = anchor_base(p8, p16, p32, b, a, hw, HW);
    float x = base[(5 + cg) * HW + hw];
    s_cost[a] = cost_fn(x, sig_obj[bA + a], sum_l1p[bA + a], ioum, fg, ib);
  }
#pragma unroll
  for (int j = 0; j < 10; ++j) s_top[tid * 10 + j] = t10[j];
  __syncthreads();

  // dyn_k = clamp(int(sum of global top-10 ious), 1, ..)
  float sum10 = 0.0f;
  for (int it = 0; it < 10; ++it) {
    float bv = -1.0f; int bi = 0;
#pragma unroll
    for (int j = 0; j < 10; ++j) {
      float v = s_top[tid * 10 + j];
      if (v > bv) { bv = v; bi = tid * 10 + j; }
    }
    s_rv[tid] = bv; s_ri[tid] = bi;
    __syncthreads();
    for (int s = 128; s > 0; s >>= 1) {
      if (tid < s) {
        if (s_rv[tid + s] > s_rv[tid]) { s_rv[tid] = s_rv[tid + s]; s_ri[tid] = s_ri[tid + s]; }
      }
      __syncthreads();
    }
    if (tid == 0) { sum10 += s_rv[0]; s_top[s_ri[0]] = -1.0f; }
    __syncthreads();
  }
  if (tid == 0) {
    int k = (int)sum10;           // truncation, matches astype(int32)
    if (k < 1) k = 1;
    s_k = k;
  }
  __syncthreads();
  int k = s_k;

  // extract k smallest costs; tie-break by smaller anchor index (stable argsort equiv).
  for (int it = 0; it < k; ++it) {
    float bv = 3.4e38f; int bi = NA;
    for (int a = tid; a < NA; a += 256) {
      float v = s_cost[a];
      if (v < bv || (v == bv && a < bi)) { bv = v; bi = a; }
    }
    s_rv[tid] = bv; s_ri[tid] = bi;
    __syncthreads();
    for (int s = 128; s > 0; s >>= 1) {
      if (tid < s) {
        float v2 = s_rv[tid + s]; int i2 = s_ri[tid + s];
        if (v2 < s_rv[tid] || (v2 == s_rv[tid] && i2 < s_ri[tid])) { s_rv[tid] = v2; s_ri[tid] = i2; }
      }
      __syncthreads();
    }
    if (tid == 0) {
      int idx = s_ri[0];
      // candidate costs < ~1.2e5; non-candidates >= ~1e9 (masked out by & fg_cand in ref)
      if (s_rv[0] < 1e8f) atomicOr(&match_mask[bA + idx], 1u << g);
      s_cost[idx] = 3.4e38f;
    }
    __syncthreads();
  }
}

// ---------- kernel C: finalize per-anchor, accumulate losses ----------
__global__ __launch_bounds__(256) void kC(const float* __restrict__ p8,
                                          const float* __restrict__ p16,
                                          const float* __restrict__ p32,
                                          const float* __restrict__ labels,
                                          const float4* __restrict__ bbox,
                                          const float* __restrict__ sig_obj,
                                          const float* __restrict__ sum_l1p,
                                          const float* __restrict__ sum_bce0,
                                          const unsigned int* __restrict__ amask,
                                          const unsigned int* __restrict__ match_mask,
                                          float* __restrict__ accum) {
  __shared__ float s_gt[NG * 5];
  __shared__ float s_red[256];
  int b = blockIdx.y, tid = threadIdx.x;
  if (tid < NG * 5) s_gt[tid] = labels[(size_t)b * NG * 5 + tid];
  __syncthreads();

  int a = blockIdx.x * 256 + tid;
  size_t bA = (size_t)b * NA;
  float li = 0.0f, oe = 0.0f, lc = 0.0f, nf = 0.0f;

  if (a < NA) {
    unsigned int m = match_mask[bA + a];
    if (m != 0u) {
      int hw, HW;
      const float* base = anchor_base(p8, p16, p32, b, a, hw, HW);
      float4 pb = bbox[bA + a];
      int mg;
      if (m & (m - 1)) {
        // multi-matched: best = argmin over ALL g of cost[g,a] (first-min tie-break)
        unsigned int am = amask[bA + a];
        float so = sig_obj[bA + a], sl = sum_l1p[bA + a];
        float bestc = 3.4e38f; mg = 0;
        for (int g = 0; g < NG; ++g) {
          float iou = iou_raw(s_gt[g * 5], s_gt[g * 5 + 1], s_gt[g * 5 + 2], s_gt[g * 5 + 3], pb);
          int cgx = (int)s_gt[g * 5 + 4];
          float x = base[(5 + cgx) * HW + hw];
          bool ib = ((am >> g) & 1u) != 0u;
          float c = cost_fn(x, so, sl, iou, true, ib);  // fg_cand is true for matched anchors
          if (c < bestc) { bestc = c; mg = g; }
        }
      } else {
        mg = __ffs(m) - 1;
      }
      float gx = s_gt[mg * 5], gy = s_gt[mg * 5 + 1];
      float gw = s_gt[mg * 5 + 2], gh = s_gt[mg * 5 + 3];
      int cg = (int)s_gt[mg * 5 + 4];
      float piou = iou_raw(gx, gy, gw, gh, pb);       // raw ious at matched g
      li = giou_loss(pb, gx, gy, gw, gh);
      float xcls = base[(5 + cg) * HW + hw];
      lc = sum_bce0[bA + a] - xcls * piou;            // bce(x,t)=bce(x,0)-x*t
      oe = base[4 * HW + hw];                         // obj logit (bce(x,1)=bce(x,0)-x)
      nf = 1.0f;
    }
  }

  // reduce 4 accumulators
  float vals[4] = {li, oe, lc, nf};
  const int slot[4] = {0, 2, 3, 4};
#pragma unroll
  for (int q = 0; q < 4; ++q) {
    s_red[tid] = vals[q];
    __syncthreads();
    for (int s = 128; s > 0; s >>= 1) {
      if (tid < s) s_red[tid] += s_red[tid + s];
      __syncthreads();
    }
    if (tid == 0) atomicAdd(&accum[slot[q]], s_red[0]);
    __syncthreads();
  }
}

// ---------- kernel D: scalar finalize ----------
__global__ void kD(const float* __restrict__ accum, float* __restrict__ out) {
  float loss_iou = accum[0];
  float loss_obj = accum[1] - accum[2];
  float loss_cls = accum[3];
  float num_fg = fmaxf(accum[4], 1.0f);
  out[0] = (5.0f * loss_iou + loss_obj + loss_cls) / num_fg;
}

// ---------- launch ----------
extern "C" void kernel_launch(void* const* d_in, const int* in_sizes, int n_in,
                              void* d_out, int out_size, void* d_ws, size_t ws_size,
                              hipStream_t stream) {
  const float* p8     = (const float*)d_in[0];
  const float* p16    = (const float*)d_in[1];
  const float* p32    = (const float*)d_in[2];
  const float* labels = (const float*)d_in[3];
  float* out = (float*)d_out;

  const size_t BA = (size_t)NB * NA;
  char* w = (char*)d_ws;
  unsigned int* match_mask = (unsigned int*)w;                 // BA u32
  float*        accum      = (float*)(w + BA * 4);             // 8 floats
  unsigned int* amask      = (unsigned int*)(w + BA * 4 + 32); // BA u32
  float4*       bbox       = (float4*)(w + BA * 8 + 32);       // BA float4 (16B-aligned)
  float*        sig_obj    = (float*)(w + BA * 8 + 32 + BA * 16);
  float*        sum_l1p    = sig_obj + BA;
  float*        sum_bce0   = sum_l1p + BA;

  // zero match_mask + accum (ws is poisoned 0xAA before every timed launch)
  hipMemsetAsync(w, 0, BA * 4 + 32, stream);

  dim3 blk(256);
  kA<<<dim3((NA + 255) / 256, NB), blk, 0, stream>>>(p8, p16, p32, labels, bbox, sig_obj,
                                                     sum_l1p, sum_bce0, amask, accum);
  kB<<<dim3(NG, NB), blk, 0, stream>>>(p8, p16, p32, labels, bbox, sig_obj, sum_l1p,
                                       amask, match_mask);
  kC<<<dim3((NA + 255) / 256, NB), blk, 0, stream>>>(p8, p16, p32, labels, bbox, sig_obj,
                                                     sum_l1p, sum_bce0, amask, match_mask, accum);
  kD<<<1, 1, 0, stream>>>(accum, out);
}

// Round 2
// 241.578 us; speedup vs baseline: 1.9237x; 1.9237x over previous
//
#include <hip/hip_runtime.h>
#include <cstdint>
#include <cstddef>

#define NA 8400   // anchors per image: 80*80 + 40*40 + 20*20
#define NB 32     // batch
#define NG 20     // ground truths per image
#define NCL 80    // classes

// ---------- fast math helpers (native v_exp/v_log/v_rcp; error ~1-2 ulp,
// accumulated effect on the ~450-magnitude output << 6.2 threshold) ----------
__device__ __forceinline__ float frcp(float x) { return __builtin_amdgcn_rcpf(x); }
__device__ __forceinline__ float sigm(float x) { return frcp(1.0f + __expf(-x)); }
// bce(x,0) = max(x,0) + log1p(exp(-|x|)); for |x|>15 the 1+e rounds to 1 (err<3e-7/term)
__device__ __forceinline__ float bce0(float x) {
  return fmaxf(x, 0.0f) + __logf(1.0f + __expf(-fabsf(x)));
}

__device__ __forceinline__ const float* anchor_base(const float* p8, const float* p16,
                                                    const float* p32, int b, int a,
                                                    int& hw, int& HW) {
  if (a < 6400)      { hw = a;        HW = 6400; return p8  + (size_t)b * 85 * 6400; }
  else if (a < 8000) { hw = a - 6400; HW = 1600; return p16 + (size_t)b * 85 * 1600; }
  hw = a - 8000; HW = 400; return p32 + (size_t)b * 85 * 400;
}

__device__ __forceinline__ float iou_raw(float gx, float gy, float gw, float gh, float4 p) {
  float gtlx = gx - gw * 0.5f, gtly = gy - gh * 0.5f;
  float gbrx = gx + gw * 0.5f, gbry = gy + gh * 0.5f;
  float ptlx = p.x - p.z * 0.5f, ptly = p.y - p.w * 0.5f;
  float pbrx = p.x + p.z * 0.5f, pbry = p.y + p.w * 0.5f;
  float tlx = fmaxf(gtlx, ptlx), tly = fmaxf(gtly, ptly);
  float brx = fminf(gbrx, pbrx), bry = fminf(gbry, pbry);
  float inter = ((tlx < brx) && (tly < bry)) ? (brx - tlx) * (bry - tly) : 0.0f;
  float ag = gw * gh, ap = p.z * p.w;
  return inter * frcp(ag + ap - inter + 1e-16f);
}

// cost = cls_cost + 3*iou_cost + 1e5*(!in_both)  (fg assumed true by callers)
__device__ __forceinline__ float cost_fn(float x, float sig_obj_v, float sum_l1p_v,
                                         float ioum, bool ib) {
  float sc  = sigm(x);
  float p   = sqrtf(sc * sig_obj_v);
  float lp  = fmaxf(__logf(p), -100.0f);
  float l1p = fmaxf(__logf(1.0f - p), -100.0f);   // log1p(-p); err ~p for p<1e-8
  float cls_cost = -((lp - l1p) + sum_l1p_v);
  float iou_cost = -__logf(ioum + 1e-8f);
  float c = cls_cost + 3.0f * iou_cost;
  if (!ib) c += 100000.0f;
  return c;
}

__device__ __forceinline__ float giou_loss(float4 bb, float gx, float gy, float gw, float gh) {
  float btlx = bb.x - bb.z * 0.5f, btly = bb.y - bb.w * 0.5f;
  float bbrx = bb.x + bb.z * 0.5f, bbry = bb.y + bb.w * 0.5f;
  float gtlx = gx - gw * 0.5f, gtly = gy - gh * 0.5f;
  float gbrx = gx + gw * 0.5f, gbry = gy + gh * 0.5f;
  float tlx = fmaxf(btlx, gtlx), tly = fmaxf(btly, gtly);
  float brx = fminf(bbrx, gbrx), bry = fminf(bbry, gbry);
  float area_b = bb.z * bb.w, area_g = gw * gh;
  float inter = ((tlx < brx) && (tly < bry)) ? (brx - tlx) * (bry - tly) : 0.0f;
  float uni = area_b + area_g - inter;
  float iou = inter / (uni + 1e-16f);
  float ctlx = fminf(btlx, gtlx), ctly = fminf(btly, gtly);
  float cbrx = fmaxf(bbrx, gbrx), cbry = fmaxf(bbry, gbry);
  float area_c = fmaxf((cbrx - ctlx) * (cbry - ctly), 1e-16f);
  float giou = iou - (area_c - uni) / area_c;
  giou = fminf(fmaxf(giou, -1.0f), 1.0f);
  return 1.0f - giou;
}

// ---------- block reduction helpers (wave shuffle + 4-entry LDS combine) ----------
__device__ __forceinline__ void block_argmin(float& v, int& i, volatile float* s_v,
                                             volatile int* s_i, int tid) {
#pragma unroll
  for (int off = 32; off; off >>= 1) {
    float ov = __shfl_down(v, off, 64);
    int   oi = __shfl_down(i, off, 64);
    if (ov < v || (ov == v && oi < i)) { v = ov; i = oi; }
  }
  if ((tid & 63) == 0) { s_v[tid >> 6] = v; s_i[tid >> 6] = i; }
  __syncthreads();
  v = s_v[0]; i = s_i[0];
#pragma unroll
  for (int w = 1; w < 4; ++w) {
    float ov = s_v[w]; int oi = s_i[w];
    if (ov < v || (ov == v && oi < i)) { v = ov; i = oi; }
  }
  // caller must __syncthreads() before s_v/s_i are reused
}

__device__ __forceinline__ void block_argmax(float& v, int& i, volatile float* s_v,
                                             volatile int* s_i, int tid) {
#pragma unroll
  for (int off = 32; off; off >>= 1) {
    float ov = __shfl_down(v, off, 64);
    int   oi = __shfl_down(i, off, 64);
    if (ov > v || (ov == v && oi < i)) { v = ov; i = oi; }
  }
  if ((tid & 63) == 0) { s_v[tid >> 6] = v; s_i[tid >> 6] = i; }
  __syncthreads();
  v = s_v[0]; i = s_i[0];
#pragma unroll
  for (int w = 1; w < 4; ++w) {
    float ov = s_v[w]; int oi = s_i[w];
    if (ov > v || (ov == v && oi < i)) { v = ov; i = oi; }
  }
}

// ---------- kernel A: decode + per-anchor precompute ----------
// accum: [0]=loss_iou [1]=loss_obj_base [2]=sum_fg obj logit [3]=loss_cls [4]=num_fg
__global__ __launch_bounds__(256) void kA(const float* __restrict__ p8,
                                          const float* __restrict__ p16,
                                          const float* __restrict__ p32,
                                          const float* __restrict__ labels,
                                          float4* __restrict__ bbox,
                                          float* __restrict__ sig_obj,
                                          float* __restrict__ sum_l1p,
                                          float* __restrict__ sum_bce0,
                                          unsigned int* __restrict__ amask,
                                          float* __restrict__ accum) {
  __shared__ float s_gt[NG * 5];
  __shared__ float s_part[4];
  int b = blockIdx.y, tid = threadIdx.x;
  if (tid < NG * 5) s_gt[tid] = labels[(size_t)b * NG * 5 + tid];
  __syncthreads();

  int a = blockIdx.x * 256 + tid;
  float bce_obj = 0.0f;
  if (a < NA) {
    int hw, HW, W, stride;
    const float* base;
    if (a < 6400)      { hw = a;        HW = 6400; W = 80; stride = 8;  base = p8  + (size_t)b * 85 * 6400; }
    else if (a < 8000) { hw = a - 6400; HW = 1600; W = 40; stride = 16; base = p16 + (size_t)b * 85 * 1600; }
    else               { hw = a - 8000; HW = 400;  W = 20; stride = 32; base = p32 + (size_t)b * 85 * 400;  }
    int xg = hw % W, yg = hw / W;
    float fs = (float)stride;

    // geometry masks first — they gate the expensive class loop
    float xc = ((float)xg + 0.5f) * fs;
    float yc = ((float)yg + 0.5f) * fs;
    float r = 2.5f * fs;
    unsigned int msk = 0u;
    bool fg = false;
#pragma unroll
    for (int g = 0; g < NG; ++g) {
      float gx = s_gt[g * 5 + 0], gy = s_gt[g * 5 + 1];
      float gw = s_gt[g * 5 + 2], gh = s_gt[g * 5 + 3];
      bool inb = (xc > gx - 0.5f * gw) && (xc < gx + 0.5f * gw) &&
                 (yc > gy - 0.5f * gh) && (yc < gy + 0.5f * gh);
      bool inc = (xc > gx - r) && (xc < gx + r) && (yc > gy - r) && (yc < gy + r);
      fg = fg || inb || inc;
      if (inb && inc) msk |= (1u << g);
    }
    if (fg) msk |= 0x80000000u;
    amask[(size_t)b * NA + a] = msk;

    float v0 = base[hw];
    float v1 = base[HW + hw];
    float v2 = base[2 * HW + hw];
    float v3 = base[3 * HW + hw];
    float obj = base[4 * HW + hw];

    bbox[(size_t)b * NA + a] = make_float4((v0 + (float)xg) * fs, (v1 + (float)yg) * fs,
                                           __expf(v2) * fs, __expf(v3) * fs);
    float so = sigm(obj);
    sig_obj[(size_t)b * NA + a] = so;
    bce_obj = bce0(obj);

    // class loop ONLY for fg candidates — sum_l1p/sum_bce0 are never read otherwise
    if (fg) {
      float sl = 0.0f, sb = 0.0f;
      for (int c = 0; c < NCL; ++c) {
        float x  = base[(5 + c) * HW + hw];
        float p  = sqrtf(sigm(x) * so);
        sl += fmaxf(__logf(1.0f - p), -100.0f);
        sb += bce0(x);
      }
      sum_l1p[(size_t)b * NA + a]  = sl;
      sum_bce0[(size_t)b * NA + a] = sb;
    }
  }

  // block-reduce bce(obj,0) over all anchors
#pragma unroll
  for (int off = 32; off; off >>= 1) bce_obj += __shfl_down(bce_obj, off, 64);
  if ((tid & 63) == 0) s_part[tid >> 6] = bce_obj;
  __syncthreads();
  if (tid == 0) atomicAdd(&accum[1], s_part[0] + s_part[1] + s_part[2] + s_part[3]);
}

// ---------- kernel B: per (b,g) cost row + dyn_k top-k selection ----------
__global__ __launch_bounds__(256) void kB(const float* __restrict__ p8,
                                          const float* __restrict__ p16,
                                          const float* __restrict__ p32,
                                          const float* __restrict__ labels,
                                          const float4* __restrict__ bbox,
                                          const float* __restrict__ sig_obj,
                                          const float* __restrict__ sum_l1p,
                                          const unsigned int* __restrict__ amask,
                                          unsigned int* __restrict__ match_mask) {
  __shared__ float s_cost[NA];        // 33.6 KB
  __shared__ float s_top[256 * 11];   // stride 11: gcd(11,32)=1 → conflict-free
  __shared__ float s_v[4];
  __shared__ int   s_i[4];

  int g = blockIdx.x, b = blockIdx.y, tid = threadIdx.x;
  size_t bA = (size_t)b * NA;

  float gx = labels[(size_t)b * NG * 5 + g * 5 + 0];
  float gy = labels[(size_t)b * NG * 5 + g * 5 + 1];
  float gw = labels[(size_t)b * NG * 5 + g * 5 + 2];
  float gh = labels[(size_t)b * NG * 5 + g * 5 + 3];
  int   cg = (int)labels[(size_t)b * NG * 5 + g * 5 + 4];

  float t10[10];
#pragma unroll
  for (int j = 0; j < 10; ++j) t10[j] = 0.0f;

  for (int a = tid; a < NA; a += 256) {
    unsigned int am = amask[bA + a];
    float c = 1e9f;                    // non-candidate: never selected (k <= 10 << #cand)
    if (am & 0x80000000u) {
      float4 pb = bbox[bA + a];
      float iou = iou_raw(gx, gy, gw, gh, pb);
      if (iou > t10[9]) {              // per-thread top-10 of masked ious, descending
        t10[9] = iou;
#pragma unroll
        for (int j = 9; j > 0; --j) {
          if (t10[j] > t10[j - 1]) { float t = t10[j]; t10[j] = t10[j - 1]; t10[j - 1] = t; }
          else break;
        }
      }
      bool ib = ((am >> g) & 1u) != 0u;
      int hw, HW;
      const float* base = anchor_base(p8, p16, p32, b, a, hw, HW);
      float x = base[(5 + cg) * HW + hw];
      c = cost_fn(x, sig_obj[bA + a], sum_l1p[bA + a], iou, ib);
    }
    s_cost[a] = c;
  }
#pragma unroll
  for (int j = 0; j < 10; ++j) s_top[tid * 11 + j] = t10[j];
  __syncthreads();

  // global top-10 of ious → dyn_k (all threads track the running sum redundantly)
  float sum10 = 0.0f;
  for (int it = 0; it < 10; ++it) {
    float bv = -1.0f; int bj = 0;
#pragma unroll
    for (int j = 0; j < 10; ++j) {
      float v = s_top[tid * 11 + j];
      if (v > bv) { bv = v; bj = j; }
    }
    int own = (tid << 4) | bj;         // tie-break by owner id; equal values → same sum
    block_argmax(bv, own, s_v, s_i, tid);
    sum10 += bv;
    if (tid == (own >> 4)) s_top[tid * 11 + (own & 15)] = -1.0f;
    __syncthreads();
  }
  int k = (int)sum10;                  // truncation matches astype(int32)
  if (k < 1) k = 1;

  // extract k smallest costs; lexicographic (cost, idx) == stable argsort semantics
  for (int it = 0; it < k; ++it) {
    float bv = 3.4e38f; int bi = NA;
    for (int a = tid; a < NA; a += 256) {
      float v = s_cost[a];
      if (v < bv || (v == bv && a < bi)) { bv = v; bi = a; }
    }
    block_argmin(bv, bi, s_v, s_i, tid);
    if (bv >= 1e8f) break;             // only non-candidates left (ref masks them anyway)
    if (tid == 0) {
      atomicOr(&match_mask[bA + bi], 1u << g);
      s_cost[bi] = 3.4e38f;
    }
    __syncthreads();
  }
}

// ---------- kernel C: finalize per-anchor, accumulate losses ----------
__global__ __launch_bounds__(256) void kC(const float* __restrict__ p8,
                                          const float* __restrict__ p16,
                                          const float* __restrict__ p32,
                                          const float* __restrict__ labels,
                                          const float4* __restrict__ bbox,
                                          const float* __restrict__ sig_obj,
                                          const float* __restrict__ sum_l1p,
                                          const float* __restrict__ sum_bce0,
                                          const unsigned int* __restrict__ amask,
                                          const unsigned int* __restrict__ match_mask,
                                          float* __restrict__ accum) {
  __shared__ float s_gt[NG * 5];
  __shared__ float s_red[16];
  int b = blockIdx.y, tid = threadIdx.x;
  if (tid < NG * 5) s_gt[tid] = labels[(size_t)b * NG * 5 + tid];
  __syncthreads();

  int a = blockIdx.x * 256 + tid;
  size_t bA = (size_t)b * NA;
  float li = 0.0f, oe = 0.0f, lc = 0.0f, nf = 0.0f;

  if (a < NA) {
    unsigned int m = match_mask[bA + a];
    if (m != 0u) {
      int hw, HW;
      const float* base = anchor_base(p8, p16, p32, b, a, hw, HW);
      float4 pb = bbox[bA + a];
      int mg;
      if (m & (m - 1)) {
        // multi-matched: best = argmin over ALL g of cost[g,a] (first-min tie-break)
        unsigned int am = amask[bA + a];
        float so = sig_obj[bA + a], sl = sum_l1p[bA + a];
        float bestc = 3.4e38f; mg = 0;
        for (int g = 0; g < NG; ++g) {
          float iou = iou_raw(s_gt[g * 5], s_gt[g * 5 + 1], s_gt[g * 5 + 2], s_gt[g * 5 + 3], pb);
          int cgx = (int)s_gt[g * 5 + 4];
          float x = base[(5 + cgx) * HW + hw];
          bool ib = ((am >> g) & 1u) != 0u;
          float c = cost_fn(x, so, sl, iou, ib);
          if (c < bestc) { bestc = c; mg = g; }
        }
      } else {
        mg = __ffs(m) - 1;
      }
      float gx = s_gt[mg * 5], gy = s_gt[mg * 5 + 1];
      float gw = s_gt[mg * 5 + 2], gh = s_gt[mg * 5 + 3];
      int cg = (int)s_gt[mg * 5 + 4];
      float piou = iou_raw(gx, gy, gw, gh, pb);
      li = giou_loss(pb, gx, gy, gw, gh);
      float xcls = base[(5 + cg) * HW + hw];
      lc = sum_bce0[bA + a] - xcls * piou;   // bce(x,t) = bce(x,0) - x*t
      oe = base[4 * HW + hw];                // obj logit: bce(x,1) = bce(x,0) - x
      nf = 1.0f;
    }
  }

  float vals[4] = {li, oe, lc, nf};
#pragma unroll
  for (int q = 0; q < 4; ++q) {
#pragma unroll
    for (int off = 32; off; off >>= 1) vals[q] += __shfl_down(vals[q], off, 64);
  }
  if ((tid & 63) == 0) {
    int wid = tid >> 6;
    s_red[wid * 4 + 0] = vals[0];
    s_red[wid * 4 + 1] = vals[1];
    s_red[wid * 4 + 2] = vals[2];
    s_red[wid * 4 + 3] = vals[3];
  }
  __syncthreads();
  if (tid < 4) {
    const int slot[4] = {0, 2, 3, 4};
    float s = s_red[tid] + s_red[4 + tid] + s_red[8 + tid] + s_red[12 + tid];
    atomicAdd(&accum[slot[tid]], s);
  }
}

// ---------- kernel D: scalar finalize ----------
__global__ void kD(const float* __restrict__ accum, float* __restrict__ out) {
  float loss_iou = accum[0];
  float loss_obj = accum[1] - accum[2];
  float loss_cls = accum[3];
  float num_fg = fmaxf(accum[4], 1.0f);
  out[0] = (5.0f * loss_iou + loss_obj + loss_cls) / num_fg;
}

// ---------- launch ----------
extern "C" void kernel_launch(void* const* d_in, const int* in_sizes, int n_in,
                              void* d_out, int out_size, void* d_ws, size_t ws_size,
                              hipStream_t stream) {
  const float* p8     = (const float*)d_in[0];
  const float* p16    = (const float*)d_in[1];
  const float* p32    = (const float*)d_in[2];
  const float* labels = (const float*)d_in[3];
  float* out = (float*)d_out;

  const size_t BA = (size_t)NB * NA;
  char* w = (char*)d_ws;
  unsigned int* match_mask = (unsigned int*)w;                 // BA u32
  float*        accum      = (float*)(w + BA * 4);             // 8 floats
  unsigned int* amask      = (unsigned int*)(w + BA * 4 + 32); // BA u32
  float4*       bbox       = (float4*)(w + BA * 8 + 32);       // BA float4 (16B aligned)
  float*        sig_obj    = (float*)(w + BA * 8 + 32 + BA * 16);
  float*        sum_l1p    = sig_obj + BA;
  float*        sum_bce0   = sum_l1p + BA;

  hipMemsetAsync(w, 0, BA * 4 + 32, stream);   // zero match_mask + accum

  dim3 blk(256);
  kA<<<dim3((NA + 255) / 256, NB), blk, 0, stream>>>(p8, p16, p32, labels, bbox, sig_obj,
                                                     sum_l1p, sum_bce0, amask, accum);
  kB<<<dim3(NG, NB), blk, 0, stream>>>(p8, p16, p32, labels, bbox, sig_obj, sum_l1p,
                                       amask, match_mask);
  kC<<<dim3((NA + 255) / 256, NB), blk, 0, stream>>>(p8, p16, p32, labels, bbox, sig_obj,
                                                     sum_l1p, sum_bce0, amask, match_mask, accum);
  kD<<<1, 1, 0, stream>>>(accum, out);
}

// Round 3
// 204.881 us; speedup vs baseline: 2.2683x; 1.1791x over previous
//
#include <hip/hip_runtime.h>
#include <cstdint>
#include <cstddef>

#define NA 8400   // anchors per image: 80*80 + 40*40 + 20*20
#define NAP 8448  // padded to 33*256 for uniform strided loops
#define NB 32     // batch
#define NG 20     // ground truths per image
#define NCL 80    // classes

// ---------- fast math ----------
__device__ __forceinline__ float frcp(float x) { return __builtin_amdgcn_rcpf(x); }
__device__ __forceinline__ float sigm(float x) { return frcp(1.0f + __expf(-x)); }
__device__ __forceinline__ float bce0(float x) {
  return fmaxf(x, 0.0f) + __logf(1.0f + __expf(-fabsf(x)));
}

__device__ __forceinline__ const float* anchor_base(const float* p8, const float* p16,
                                                    const float* p32, int b, int a,
                                                    int& hw, int& HW) {
  if (a < 6400)      { hw = a;        HW = 6400; return p8  + (size_t)b * 85 * 6400; }
  else if (a < 8000) { hw = a - 6400; HW = 1600; return p16 + (size_t)b * 85 * 1600; }
  hw = a - 8000; HW = 400; return p32 + (size_t)b * 85 * 400;
}

__device__ __forceinline__ float iou_raw(float gx, float gy, float gw, float gh, float4 p) {
  float gtlx = gx - gw * 0.5f, gtly = gy - gh * 0.5f;
  float gbrx = gx + gw * 0.5f, gbry = gy + gh * 0.5f;
  float ptlx = p.x - p.z * 0.5f, ptly = p.y - p.w * 0.5f;
  float pbrx = p.x + p.z * 0.5f, pbry = p.y + p.w * 0.5f;
  float tlx = fmaxf(gtlx, ptlx), tly = fmaxf(gtly, ptly);
  float brx = fminf(gbrx, pbrx), bry = fminf(gbry, pbry);
  float inter = ((tlx < brx) && (tly < bry)) ? (brx - tlx) * (bry - tly) : 0.0f;
  float ag = gw * gh, ap = p.z * p.w;
  return inter * frcp(ag + ap - inter + 1e-16f);
}

__device__ __forceinline__ float giou_loss(float4 bb, float gx, float gy, float gw, float gh) {
  float btlx = bb.x - bb.z * 0.5f, btly = bb.y - bb.w * 0.5f;
  float bbrx = bb.x + bb.z * 0.5f, bbry = bb.y + bb.w * 0.5f;
  float gtlx = gx - gw * 0.5f, gtly = gy - gh * 0.5f;
  float gbrx = gx + gw * 0.5f, gbry = gy + gh * 0.5f;
  float tlx = fmaxf(btlx, gtlx), tly = fmaxf(btly, gtly);
  float brx = fminf(bbrx, gbrx), bry = fminf(bbry, gbry);
  float area_b = bb.z * bb.w, area_g = gw * gh;
  float inter = ((tlx < brx) && (tly < bry)) ? (brx - tlx) * (bry - tly) : 0.0f;
  float uni = area_b + area_g - inter;
  float iou = inter / (uni + 1e-16f);
  float ctlx = fminf(btlx, gtlx), ctly = fminf(btly, gtly);
  float cbrx = fmaxf(bbrx, gbrx), cbry = fmaxf(bbry, gbry);
  float area_c = fmaxf((cbrx - ctlx) * (cbry - ctly), 1e-16f);
  float giou = iou - (area_c - uni) / area_c;
  giou = fminf(fmaxf(giou, -1.0f), 1.0f);
  return 1.0f - giou;
}

__device__ __forceinline__ void block_argmin(float& v, int& i, volatile float* s_v,
                                             volatile int* s_i, int tid) {
#pragma unroll
  for (int off = 32; off; off >>= 1) {
    float ov = __shfl_down(v, off, 64);
    int   oi = __shfl_down(i, off, 64);
    if (ov < v || (ov == v && oi < i)) { v = ov; i = oi; }
  }
  if ((tid & 63) == 0) { s_v[tid >> 6] = v; s_i[tid >> 6] = i; }
  __syncthreads();
  v = s_v[0]; i = s_i[0];
#pragma unroll
  for (int w = 1; w < 4; ++w) {
    float ov = s_v[w]; int oi = s_i[w];
    if (ov < v || (ov == v && oi < i)) { v = ov; i = oi; }
  }
  // caller must __syncthreads() before s_v/s_i are rewritten
}

// ---------- kernel A: decode + per-anchor precompute + w_tbl build ----------
// accum: [0]=loss_iou [1]=loss_obj_base [2]=sum_fg obj logit [3]=loss_cls [4]=num_fg
__global__ __launch_bounds__(256) void kA(const float* __restrict__ p8,
                                          const float* __restrict__ p16,
                                          const float* __restrict__ p32,
                                          const float* __restrict__ labels,
                                          float4* __restrict__ bbox,
                                          float* __restrict__ sum_l1p,
                                          float* __restrict__ sum_bce0,
                                          float* __restrict__ w_tbl,
                                          unsigned int* __restrict__ amask,
                                          unsigned int* __restrict__ match_mask,
                                          float* __restrict__ accum) {
  __shared__ float s_gt[NG * 5];
  __shared__ unsigned int s_gmask[NCL];   // class -> bitmap of g's with that class
  __shared__ float s_part[4];
  int b = blockIdx.y, tid = threadIdx.x;
  if (tid < NG * 5) s_gt[tid] = labels[(size_t)b * NG * 5 + tid];
  if (tid >= 128 && tid < 128 + NCL) s_gmask[tid - 128] = 0u;
  __syncthreads();
  if (tid < NG) { int c = (int)s_gt[tid * 5 + 4]; atomicOr(&s_gmask[c], 1u << tid); }
  __syncthreads();

  int a = blockIdx.x * 256 + tid;
  size_t ba = (size_t)b * NAP + a;
  match_mask[ba] = 0u;                    // kB runs strictly after kA
  float bce_obj = 0.0f;
  if (a < NA) {
    int hw, HW, W, stride;
    const float* base;
    if (a < 6400)      { hw = a;        HW = 6400; W = 80; stride = 8;  base = p8  + (size_t)b * 85 * 6400; }
    else if (a < 8000) { hw = a - 6400; HW = 1600; W = 40; stride = 16; base = p16 + (size_t)b * 85 * 1600; }
    else               { hw = a - 8000; HW = 400;  W = 20; stride = 32; base = p32 + (size_t)b * 85 * 400;  }
    int xg = hw % W, yg = hw / W;
    float fs = (float)stride;

    // geometry first — gates everything expensive
    float xc = ((float)xg + 0.5f) * fs;
    float yc = ((float)yg + 0.5f) * fs;
    float r = 2.5f * fs;
    unsigned int msk = 0u;
    bool fg = false;
#pragma unroll
    for (int g = 0; g < NG; ++g) {
      float gx = s_gt[g * 5 + 0], gy = s_gt[g * 5 + 1];
      float gw = s_gt[g * 5 + 2], gh = s_gt[g * 5 + 3];
      bool inb = (xc > gx - 0.5f * gw) && (xc < gx + 0.5f * gw) &&
                 (yc > gy - 0.5f * gh) && (yc < gy + 0.5f * gh);
      bool inc = (xc > gx - r) && (xc < gx + r) && (yc > gy - r) && (yc < gy + r);
      fg = fg || inb || inc;
      if (inb && inc) msk |= (1u << g);
    }
    if (fg) msk |= 0x80000000u;
    amask[ba] = msk;

    float obj = base[4 * HW + hw];
    float so = sigm(obj);
    bce_obj = bce0(obj);

    if (fg) {
      float v0 = base[hw];
      float v1 = base[HW + hw];
      float v2 = base[2 * HW + hw];
      float v3 = base[3 * HW + hw];
      bbox[ba] = make_float4((v0 + (float)xg) * fs, (v1 + (float)yg) * fs,
                             __expf(v2) * fs, __expf(v3) * fs);
      float sl = 0.0f, sb = 0.0f;
      // 8-wide batched loads: 8 independent VMEM ops in flight per batch
      for (int cc = 0; cc < NCL; cc += 8) {
        float xs[8];
#pragma unroll
        for (int j = 0; j < 8; ++j) xs[j] = base[(5 + cc + j) * HW + hw];
#pragma unroll
        for (int j = 0; j < 8; ++j) {
          float x = xs[j];
          float p = sqrtf(sigm(x) * so);
          float l1p = fmaxf(__logf(1.0f - p), -100.0f);
          sl += l1p;
          sb += bce0(x);
          unsigned int m = s_gmask[cc + j];
          if (m) {                         // wave-uniform branch
            float w = fmaxf(__logf(p), -100.0f) - l1p;
            do {
              int g = __ffs(m) - 1; m &= m - 1;
              w_tbl[((size_t)b * NG + g) * NAP + a] = w;
            } while (m);
          }
        }
      }
      sum_l1p[ba] = sl;
      sum_bce0[ba] = sb;
    }
  } else {
    amask[ba] = 0u;                       // pad: never a candidate
  }

#pragma unroll
  for (int off = 32; off; off >>= 1) bce_obj += __shfl_down(bce_obj, off, 64);
  if ((tid & 63) == 0) s_part[tid >> 6] = bce_obj;
  __syncthreads();
  if (tid == 0) atomicAdd(&accum[1], s_part[0] + s_part[1] + s_part[2] + s_part[3]);
}

// ---------- kernel B: per (b,g) cost row + dyn_k top-k (streaming, branchless fill) ----------
__global__ __launch_bounds__(256) void kB(const float* __restrict__ labels,
                                          const float4* __restrict__ bbox,
                                          const float* __restrict__ sum_l1p,
                                          const float* __restrict__ w_tbl,
                                          const unsigned int* __restrict__ amask,
                                          unsigned int* __restrict__ match_mask) {
  __shared__ float s_cost[NAP];   // 33 KB
  __shared__ float s_wt[4 * 10];
  __shared__ float s_v[4];
  __shared__ int   s_i[4];
  __shared__ int   s_k;

  int g = blockIdx.x, b = blockIdx.y, tid = threadIdx.x;
  int lane = tid & 63, wid = tid >> 6;
  size_t bA = (size_t)b * NAP;
  const float* __restrict__ wg = w_tbl + ((size_t)b * NG + g) * NAP;

  float gx = labels[(size_t)b * NG * 5 + g * 5 + 0];
  float gy = labels[(size_t)b * NG * 5 + g * 5 + 1];
  float gw = labels[(size_t)b * NG * 5 + g * 5 + 2];
  float gh = labels[(size_t)b * NG * 5 + g * 5 + 3];

  float t10[10];
#pragma unroll
  for (int j = 0; j < 10; ++j) t10[j] = 0.0f;

  // fill: 33 uniform iterations, 3-wide batches, 12 independent loads in flight
  for (int i0 = 0; i0 < 33; i0 += 3) {
    unsigned int am[3]; float wv[3], sl[3]; float4 pb[3];
#pragma unroll
    for (int j = 0; j < 3; ++j) {
      int a = tid + (i0 + j) * 256;
      am[j] = amask[bA + a];
      wv[j] = wg[a];
      sl[j] = sum_l1p[bA + a];
      pb[j] = bbox[bA + a];
    }
#pragma unroll
    for (int j = 0; j < 3; ++j) {
      int a = tid + (i0 + j) * 256;
      bool fg = (am[j] & 0x80000000u) != 0u;
      float iou = iou_raw(gx, gy, gw, gh, pb[j]);   // NaN-safe for poison bbox
      float ioum = fg ? iou : 0.0f;
      if (ioum > t10[9]) {
        t10[9] = ioum;
#pragma unroll
        for (int q = 9; q > 0; --q) {
          if (t10[q] > t10[q - 1]) { float t = t10[q]; t10[q] = t10[q - 1]; t10[q - 1] = t; }
          else break;
        }
      }
      float c = -(wv[j] + sl[j]) - 3.0f * __logf(ioum + 1e-8f);
      if (!((am[j] >> g) & 1u)) c += 100000.0f;
      if (!fg) c = 1e9f;
      s_cost[a] = c;
    }
  }

  // per-wave top-10 extraction: registers + shuffles, no syncs
  for (int r = 0; r < 10; ++r) {
    float v = t10[0];
    float bv = v;
#pragma unroll
    for (int off = 32; off; off >>= 1) bv = fmaxf(bv, __shfl_down(bv, off, 64));
    bv = __shfl(bv, 0, 64);
    unsigned long long won = __ballot(v == bv);
    if (lane == __ffsll(won) - 1) {       // exactly one popper per wave
#pragma unroll
      for (int q = 0; q < 9; ++q) t10[q] = t10[q + 1];
      t10[9] = -1.0f;
    }
    if (lane == 0) s_wt[wid * 10 + r] = bv;
  }
  __syncthreads();

  if (tid == 0) {                         // merge 4 sorted-desc lists, take top-10 sum
    int p0 = 0, p1 = 0, p2 = 0, p3 = 0;
    float s = 0.0f;
    for (int r = 0; r < 10; ++r) {
      float v0 = (p0 < 10) ? s_wt[p0]      : -2.0f;
      float v1 = (p1 < 10) ? s_wt[10 + p1] : -2.0f;
      float v2 = (p2 < 10) ? s_wt[20 + p2] : -2.0f;
      float v3 = (p3 < 10) ? s_wt[30 + p3] : -2.0f;
      float m01 = fmaxf(v0, v1), m23 = fmaxf(v2, v3);
      float m = fmaxf(m01, m23);
      s += m;
      if (m == v0) ++p0; else if (m == v1) ++p1; else if (m == v2) ++p2; else ++p3;
    }
    int k = (int)s;                       // truncation matches astype(int32)
    if (k < 1) k = 1;
    s_k = k;
  }
  __syncthreads();
  int k = s_k;

  // extract k smallest costs; (cost, idx) lexicographic == stable argsort
  for (int it = 0; it < k; ++it) {
    float bv = 3.4e38f; int bi = NAP;
    for (int a = tid; a < NAP; a += 256) {
      float v = s_cost[a];
      if (v < bv || (v == bv && a < bi)) { bv = v; bi = a; }
    }
    block_argmin(bv, bi, s_v, s_i, tid);
    if (bv >= 1e8f) break;                // only non-candidates left
    if (tid == 0) {
      atomicOr(&match_mask[bA + bi], 1u << g);
      s_cost[bi] = 3.4e38f;
    }
    __syncthreads();
  }
}

// ---------- kernel C: finalize per-anchor, accumulate losses ----------
__global__ __launch_bounds__(256) void kC(const float* __restrict__ p8,
                                          const float* __restrict__ p16,
                                          const float* __restrict__ p32,
                                          const float* __restrict__ labels,
                                          const float4* __restrict__ bbox,
                                          const float* __restrict__ sum_l1p,
                                          const float* __restrict__ sum_bce0,
                                          const float* __restrict__ w_tbl,
                                          const unsigned int* __restrict__ amask,
                                          const unsigned int* __restrict__ match_mask,
                                          float* __restrict__ accum) {
  __shared__ float s_gt[NG * 5];
  __shared__ float s_red[16];
  int b = blockIdx.y, tid = threadIdx.x;
  if (tid < NG * 5) s_gt[tid] = labels[(size_t)b * NG * 5 + tid];
  __syncthreads();

  int a = blockIdx.x * 256 + tid;
  size_t ba = (size_t)b * NAP + a;
  float li = 0.0f, oe = 0.0f, lc = 0.0f, nf = 0.0f;

  if (a < NA) {
    unsigned int m = match_mask[ba];
    if (m != 0u) {
      int hw, HW;
      const float* base = anchor_base(p8, p16, p32, b, a, hw, HW);
      float4 pb = bbox[ba];
      int mg;
      if (m & (m - 1)) {
        // multi-matched: argmin over ALL g of cost (same formula as kB)
        unsigned int am = amask[ba];
        float sl = sum_l1p[ba];
        float bestc = 3.4e38f; mg = 0;
#pragma unroll 4
        for (int g = 0; g < NG; ++g) {
          float iou = iou_raw(s_gt[g * 5], s_gt[g * 5 + 1], s_gt[g * 5 + 2], s_gt[g * 5 + 3], pb);
          float wv = w_tbl[((size_t)b * NG + g) * NAP + a];
          float c = -(wv + sl) - 3.0f * __logf(iou + 1e-8f);
          if (!((am >> g) & 1u)) c += 100000.0f;
          if (c < bestc) { bestc = c; mg = g; }
        }
      } else {
        mg = __ffs(m) - 1;
      }
      float gx = s_gt[mg * 5], gy = s_gt[mg * 5 + 1];
      float gw = s_gt[mg * 5 + 2], gh = s_gt[mg * 5 + 3];
      int cg = (int)s_gt[mg * 5 + 4];
      float piou = iou_raw(gx, gy, gw, gh, pb);
      li = giou_loss(pb, gx, gy, gw, gh);
      float xcls = base[(5 + cg) * HW + hw];
      lc = sum_bce0[ba] - xcls * piou;    // bce(x,t) = bce(x,0) - x*t
      oe = base[4 * HW + hw];             // obj logit: bce(x,1) = bce(x,0) - x
      nf = 1.0f;
    }
  }

  float vals[4] = {li, oe, lc, nf};
#pragma unroll
  for (int q = 0; q < 4; ++q) {
#pragma unroll
    for (int off = 32; off; off >>= 1) vals[q] += __shfl_down(vals[q], off, 64);
  }
  if ((tid & 63) == 0) {
    int wid = tid >> 6;
    s_red[wid * 4 + 0] = vals[0];
    s_red[wid * 4 + 1] = vals[1];
    s_red[wid * 4 + 2] = vals[2];
    s_red[wid * 4 + 3] = vals[3];
  }
  __syncthreads();
  if (tid < 4) {
    const int slot[4] = {0, 2, 3, 4};
    float s = s_red[tid] + s_red[4 + tid] + s_red[8 + tid] + s_red[12 + tid];
    atomicAdd(&accum[slot[tid]], s);
  }
}

// ---------- kernel D ----------
__global__ void kD(const float* __restrict__ accum, float* __restrict__ out) {
  float loss_iou = accum[0];
  float loss_obj = accum[1] - accum[2];
  float loss_cls = accum[3];
  float num_fg = fmaxf(accum[4], 1.0f);
  out[0] = (5.0f * loss_iou + loss_obj + loss_cls) / num_fg;
}

// ---------- launch ----------
extern "C" void kernel_launch(void* const* d_in, const int* in_sizes, int n_in,
                              void* d_out, int out_size, void* d_ws, size_t ws_size,
                              hipStream_t stream) {
  const float* p8     = (const float*)d_in[0];
  const float* p16    = (const float*)d_in[1];
  const float* p32    = (const float*)d_in[2];
  const float* labels = (const float*)d_in[3];
  float* out = (float*)d_out;

  const size_t BAP = (size_t)NB * NAP;     // 270336
  char* w = (char*)d_ws;
  float4*       bbox       = (float4*)w;                          // BAP*16 (16B aligned)
  unsigned int* match_mask = (unsigned int*)(w + BAP * 16);       // BAP*4
  unsigned int* amask      = (unsigned int*)(w + BAP * 20);       // BAP*4
  float*        sum_l1p    = (float*)(w + BAP * 24);              // BAP*4
  float*        sum_bce0   = (float*)(w + BAP * 28);              // BAP*4
  float*        w_tbl      = (float*)(w + BAP * 32);              // NB*NG*NAP*4 = 21.6 MB
  float*        accum      = (float*)(w + BAP * 32 + (size_t)NB * NG * NAP * 4);

  hipMemsetAsync(accum, 0, 32, stream);    // 8 floats; match_mask zeroed in kA

  dim3 blk(256);
  kA<<<dim3(NAP / 256, NB), blk, 0, stream>>>(p8, p16, p32, labels, bbox, sum_l1p,
                                              sum_bce0, w_tbl, amask, match_mask, accum);
  kB<<<dim3(NG, NB), blk, 0, stream>>>(labels, bbox, sum_l1p, w_tbl, amask, match_mask);
  kC<<<dim3(NAP / 256, NB), blk, 0, stream>>>(p8, p16, p32, labels, bbox, sum_l1p,
                                              sum_bce0, w_tbl, amask, match_mask, accum);
  kD<<<1, 1, 0, stream>>>(accum, out);
}

// Round 4
// 196.535 us; speedup vs baseline: 2.3646x; 1.0425x over previous
//
#include <hip/hip_runtime.h>
#include <cstdint>
#include <cstddef>

#define NA 8400   // anchors per image: 80*80 + 40*40 + 20*20
#define NAP 8448  // padded stride (33*256)
#define NB 32     // batch
#define NG 20     // ground truths per image
#define NCL 80    // classes

// ---------- fast math ----------
__device__ __forceinline__ float frcp(float x) { return __builtin_amdgcn_rcpf(x); }
__device__ __forceinline__ float bce0(float x) {
  return fmaxf(x, 0.0f) + __logf(1.0f + __expf(-fabsf(x)));
}

// per-level info; xg/yg use per-branch constant division (magic-mul)
__device__ __forceinline__ void anchor_info(int a, const float* p8, const float* p16,
                                            const float* p32, int b, const float*& base,
                                            int& hw, int& HW, int& xg, int& yg, float& fs) {
  if (a < 6400)      { hw = a;        HW = 6400; xg = hw % 80; yg = hw / 80; fs = 8.f;
                       base = p8  + (size_t)b * 85 * 6400; }
  else if (a < 8000) { hw = a - 6400; HW = 1600; xg = hw % 40; yg = hw / 40; fs = 16.f;
                       base = p16 + (size_t)b * 85 * 1600; }
  else               { hw = a - 8000; HW = 400;  xg = hw % 20; yg = hw / 20; fs = 32.f;
                       base = p32 + (size_t)b * 85 * 400; }
}

__device__ __forceinline__ float iou_raw(float gx, float gy, float gw, float gh, float4 p) {
  float gtlx = gx - gw * 0.5f, gtly = gy - gh * 0.5f;
  float gbrx = gx + gw * 0.5f, gbry = gy + gh * 0.5f;
  float ptlx = p.x - p.z * 0.5f, ptly = p.y - p.w * 0.5f;
  float pbrx = p.x + p.z * 0.5f, pbry = p.y + p.w * 0.5f;
  float tlx = fmaxf(gtlx, ptlx), tly = fmaxf(gtly, ptly);
  float brx = fminf(gbrx, pbrx), bry = fminf(gbry, pbry);
  float inter = ((tlx < brx) && (tly < bry)) ? (brx - tlx) * (bry - tly) : 0.0f;
  float ag = gw * gh, ap = p.z * p.w;
  return inter * frcp(ag + ap - inter + 1e-16f);
}

__device__ __forceinline__ float giou_loss(float4 bb, float gx, float gy, float gw, float gh) {
  float btlx = bb.x - bb.z * 0.5f, btly = bb.y - bb.w * 0.5f;
  float bbrx = bb.x + bb.z * 0.5f, bbry = bb.y + bb.w * 0.5f;
  float gtlx = gx - gw * 0.5f, gtly = gy - gh * 0.5f;
  float gbrx = gx + gw * 0.5f, gbry = gy + gh * 0.5f;
  float tlx = fmaxf(btlx, gtlx), tly = fmaxf(btly, gtly);
  float brx = fminf(bbrx, gbrx), bry = fminf(bbry, gbry);
  float area_b = bb.z * bb.w, area_g = gw * gh;
  float inter = ((tlx < brx) && (tly < bry)) ? (brx - tlx) * (bry - tly) : 0.0f;
  float uni = area_b + area_g - inter;
  float iou = inter / (uni + 1e-16f);
  float ctlx = fminf(btlx, gtlx), ctly = fminf(btly, gtly);
  float cbrx = fmaxf(bbrx, gbrx), cbry = fmaxf(bbry, gbry);
  float area_c = fmaxf((cbrx - ctlx) * (cbry - ctly), 1e-16f);
  float giou = iou - (area_c - uni) / area_c;
  giou = fminf(fmaxf(giou, -1.0f), 1.0f);
  return 1.0f - giou;
}

__device__ __forceinline__ void block_argmin(float& v, int& i, volatile float* s_v,
                                             volatile int* s_i, int tid) {
#pragma unroll
  for (int off = 32; off; off >>= 1) {
    float ov = __shfl_down(v, off, 64);
    int   oi = __shfl_down(i, off, 64);
    if (ov < v || (ov == v && oi < i)) { v = ov; i = oi; }
  }
  if ((tid & 63) == 0) { s_v[tid >> 6] = v; s_i[tid >> 6] = i; }
  __syncthreads();
  v = s_v[0]; i = s_i[0];
#pragma unroll
  for (int w = 1; w < 4; ++w) {
    float ov = s_v[w]; int oi = s_i[w];
    if (ov < v || (ov == v && oi < i)) { v = ov; i = oi; }
  }
}

// ---------- kA0: geometry + ORDERED fg compaction + obj-BCE sum (1 block/image) ----------
__global__ __launch_bounds__(1024) void kA0(const float* __restrict__ p8,
                                            const float* __restrict__ p16,
                                            const float* __restrict__ p32,
                                            const float* __restrict__ labels,
                                            unsigned int* __restrict__ am_c,
                                            int* __restrict__ fg_list,
                                            int* __restrict__ n_fg,
                                            unsigned int* __restrict__ match_c,
                                            float* __restrict__ accum) {
  __shared__ float s_gt[NG * 4];
  __shared__ unsigned int s_wcnt[16];
  __shared__ unsigned int s_base;
  __shared__ float s_part[16];
  int b = blockIdx.x, tid = threadIdx.x, lane = tid & 63, wid = tid >> 6;
  if (tid < NG) {
    s_gt[tid * 4 + 0] = labels[((size_t)b * NG + tid) * 5 + 0];
    s_gt[tid * 4 + 1] = labels[((size_t)b * NG + tid) * 5 + 1];
    s_gt[tid * 4 + 2] = labels[((size_t)b * NG + tid) * 5 + 2];
    s_gt[tid * 4 + 3] = labels[((size_t)b * NG + tid) * 5 + 3];
  }
  if (tid == 0) s_base = 0u;
  __syncthreads();

  float bce_obj = 0.0f;
  for (int it = 0; it < 9; ++it) {
    int a = it * 1024 + tid;
    unsigned int msk = 0u;
    bool fg = false;
    if (a < NA) {
      const float* base; int hw, HW, xg, yg; float fs;
      anchor_info(a, p8, p16, p32, b, base, hw, HW, xg, yg, fs);
      float obj = base[4 * HW + hw];
      bce_obj += bce0(obj);
      float xc = ((float)xg + 0.5f) * fs;
      float yc = ((float)yg + 0.5f) * fs;
      float r = 2.5f * fs;
#pragma unroll
      for (int g = 0; g < NG; ++g) {
        float gx = s_gt[g * 4 + 0], gy = s_gt[g * 4 + 1];
        float gw = s_gt[g * 4 + 2], gh = s_gt[g * 4 + 3];
        bool inb = (xc > gx - 0.5f * gw) && (xc < gx + 0.5f * gw) &&
                   (yc > gy - 0.5f * gh) && (yc < gy + 0.5f * gh);
        bool inc = (xc > gx - r) && (xc < gx + r) && (yc > gy - r) && (yc < gy + r);
        fg = fg || inb || inc;
        if (inb && inc) msk |= (1u << g);
      }
    }
    if (a < NAP) match_c[(size_t)b * NAP + a] = 0u;

    unsigned long long bm = __ballot(fg);
    if (lane == 0) s_wcnt[wid] = (unsigned int)__popcll(bm);
    __syncthreads();
    unsigned int pos = s_base;
    for (int w = 0; w < wid; ++w) pos += s_wcnt[w];
    if (fg) {
      pos += (unsigned int)__popcll(bm & ((1ull << lane) - 1ull));
      fg_list[(size_t)b * NAP + pos] = a;
      am_c[(size_t)b * NAP + pos] = msk | 0x80000000u;
    }
    __syncthreads();
    if (tid == 0) {
      unsigned int t = 0;
      for (int w = 0; w < 16; ++w) t += s_wcnt[w];
      s_base += t;
    }
    __syncthreads();
  }
  if (tid == 0) n_fg[b] = (int)s_base;

#pragma unroll
  for (int off = 32; off; off >>= 1) bce_obj += __shfl_down(bce_obj, off, 64);
  if (lane == 0) s_part[wid] = bce_obj;
  __syncthreads();
  if (tid == 0) {
    float t = 0.0f;
    for (int w = 0; w < 16; ++w) t += s_part[w];
    atomicAdd(&accum[1], t);
  }
}

// ---------- kA1: heavy per-fg-anchor pass (balanced over compacted list) ----------
__global__ __launch_bounds__(256) void kA1(const float* __restrict__ p8,
                                           const float* __restrict__ p16,
                                           const float* __restrict__ p32,
                                           const float* __restrict__ labels,
                                           const int* __restrict__ fg_list,
                                           const int* __restrict__ n_fg,
                                           float4* __restrict__ bbox_c,
                                           float* __restrict__ sl_c,
                                           float* __restrict__ sb_c,
                                           float* __restrict__ w_c) {
  __shared__ unsigned int s_gmask[NCL];   // class -> bitmap of g's with that class
  int b = blockIdx.y, tid = threadIdx.x;
  if (tid < NCL) s_gmask[tid] = 0u;
  __syncthreads();
  if (tid < NG) {
    int c = (int)labels[((size_t)b * NG + tid) * 5 + 4];
    atomicOr(&s_gmask[c], 1u << tid);
  }
  __syncthreads();

  int n = n_fg[b];
  for (int ci = blockIdx.x * 256 + tid; ci < n; ci += gridDim.x * 256) {
    int a = fg_list[(size_t)b * NAP + ci];
    const float* base; int hw, HW, xg, yg; float fs;
    anchor_info(a, p8, p16, p32, b, base, hw, HW, xg, yg, fs);

    float obj = base[4 * HW + hw];
    float v0 = base[hw];
    float v1 = base[HW + hw];
    float v2 = base[2 * HW + hw];
    float v3 = base[3 * HW + hw];
    bbox_c[(size_t)b * NAP + ci] = make_float4((v0 + (float)xg) * fs, (v1 + (float)yg) * fs,
                                               __expf(v2) * fs, __expf(v3) * fs);
    // log(sigmoid(obj)) = min(obj,0) - log(1+exp(-|obj|))
    float uo  = __logf(1.0f + __expf(-fabsf(obj)));
    float lso = fminf(obj, 0.0f) - uo;

    float sl = 0.0f, sb = 0.0f;
    for (int cc = 0; cc < NCL; cc += 8) {
      float xs[8];
#pragma unroll
      for (int j = 0; j < 8; ++j) xs[j] = base[(5 + cc + j) * HW + hw];
#pragma unroll
      for (int j = 0; j < 8; ++j) {
        float x = xs[j];
        float u = __logf(1.0f + __expf(-fabsf(x)));
        sb += fmaxf(x, 0.0f) + u;                 // bce(x,0)
        float lsx = fminf(x, 0.0f) - u;           // log(sigmoid(x))
        float lpr = 0.5f * (lsx + lso);           // log p  (p = sqrt(sx*so))
        float p   = __expf(lpr);
        float l1p = fmaxf(__logf(1.0f - p), -100.0f);
        sl += l1p;
        unsigned int m = s_gmask[cc + j];
        if (m) {                                  // wave-uniform branch
          float w = fmaxf(lpr, -100.0f) - l1p;    // lp - l1p
          do {
            int g = __ffs(m) - 1; m &= m - 1;
            w_c[((size_t)b * NG + g) * NAP + ci] = w;
          } while (m);
        }
      }
    }
    sl_c[(size_t)b * NAP + ci] = sl;
    sb_c[(size_t)b * NAP + ci] = sb;
  }
}

// ---------- kB: per (b,g) cost row over COMPACTED candidates + dyn_k top-k ----------
__global__ __launch_bounds__(256) void kB(const float* __restrict__ labels,
                                          const float4* __restrict__ bbox_c,
                                          const float* __restrict__ sl_c,
                                          const float* __restrict__ w_c,
                                          const unsigned int* __restrict__ am_c,
                                          const int* __restrict__ n_fg,
                                          unsigned int* __restrict__ match_c) {
  __shared__ float s_cost[NAP];   // 33 KB (only n used)
  __shared__ float s_wt[4 * 10];
  __shared__ float s_v[4];
  __shared__ int   s_i[4];
  __shared__ int   s_k;

  int g = blockIdx.x, b = blockIdx.y, tid = threadIdx.x;
  int lane = tid & 63, wid = tid >> 6;
  int n = n_fg[b];
  size_t bo = (size_t)b * NAP;
  const float* __restrict__ wg = w_c + ((size_t)b * NG + g) * NAP;

  float gx = labels[((size_t)b * NG + g) * 5 + 0];
  float gy = labels[((size_t)b * NG + g) * 5 + 1];
  float gw = labels[((size_t)b * NG + g) * 5 + 2];
  float gh = labels[((size_t)b * NG + g) * 5 + 3];

  float t10[10];
#pragma unroll
  for (int j = 0; j < 10; ++j) t10[j] = 0.0f;

  for (int ci = tid; ci < n; ci += 256) {
    unsigned int am = am_c[bo + ci];
    float wv = wg[ci];
    float sl = sl_c[bo + ci];
    float4 pb = bbox_c[bo + ci];
    float iou = iou_raw(gx, gy, gw, gh, pb);
    if (iou > t10[9]) {
      t10[9] = iou;
#pragma unroll
      for (int q = 9; q > 0; --q) {
        if (t10[q] > t10[q - 1]) { float t = t10[q]; t10[q] = t10[q - 1]; t10[q - 1] = t; }
        else break;
      }
    }
    float c = -(wv + sl) - 3.0f * __logf(iou + 1e-8f);
    if (!((am >> g) & 1u)) c += 100000.0f;
    s_cost[ci] = c;
  }

  // per-wave top-10 extraction (regs+shuffles, no syncs), then 4-list merge
  for (int r = 0; r < 10; ++r) {
    float v = t10[0];
    float bv = v;
#pragma unroll
    for (int off = 32; off; off >>= 1) bv = fmaxf(bv, __shfl_down(bv, off, 64));
    bv = __shfl(bv, 0, 64);
    unsigned long long won = __ballot(v == bv);
    if (lane == __ffsll(won) - 1) {
#pragma unroll
      for (int q = 0; q < 9; ++q) t10[q] = t10[q + 1];
      t10[9] = -1.0f;
    }
    if (lane == 0) s_wt[wid * 10 + r] = bv;
  }
  __syncthreads();

  if (tid == 0) {
    int p0 = 0, p1 = 0, p2 = 0, p3 = 0;
    float s = 0.0f;
    for (int r = 0; r < 10; ++r) {
      float v0 = (p0 < 10) ? s_wt[p0]      : -2.0f;
      float v1 = (p1 < 10) ? s_wt[10 + p1] : -2.0f;
      float v2 = (p2 < 10) ? s_wt[20 + p2] : -2.0f;
      float v3 = (p3 < 10) ? s_wt[30 + p3] : -2.0f;
      float m = fmaxf(fmaxf(v0, v1), fmaxf(v2, v3));
      s += m;
      if (m == v0) ++p0; else if (m == v1) ++p1; else if (m == v2) ++p2; else ++p3;
    }
    int k = (int)s;                 // truncation matches astype(int32)
    if (k < 1) k = 1;
    s_k = k;
  }
  __syncthreads();
  int k = s_k;

  // extract k smallest; (cost, ci) lexicographic == stable argsort (ci order == anchor order)
  for (int it = 0; it < k; ++it) {
    float bv = 3.4e38f; int bi = NAP;
    for (int ci = tid; ci < n; ci += 256) {
      float v = s_cost[ci];
      if (v < bv || (v == bv && ci < bi)) { bv = v; bi = ci; }
    }
    block_argmin(bv, bi, s_v, s_i, tid);
    if (bv >= 1e8f) break;          // exhausted real candidates (cost <= ~1.1e5)
    if (tid == 0) {
      atomicOr(&match_c[bo + bi], 1u << g);
      s_cost[bi] = 3.4e38f;
    }
    __syncthreads();
  }
}

// ---------- kC: finalize matched anchors (compacted) ----------
__global__ __launch_bounds__(256) void kC(const float* __restrict__ p8,
                                          const float* __restrict__ p16,
                                          const float* __restrict__ p32,
                                          const float* __restrict__ labels,
                                          const float4* __restrict__ bbox_c,
                                          const float* __restrict__ sl_c,
                                          const float* __restrict__ sb_c,
                                          const float* __restrict__ w_c,
                                          const unsigned int* __restrict__ am_c,
                                          const int* __restrict__ fg_list,
                                          const int* __restrict__ n_fg,
                                          const unsigned int* __restrict__ match_c,
                                          float* __restrict__ accum) {
  __shared__ float s_gt[NG * 5];
  __shared__ float s_red[16];
  int b = blockIdx.y, tid = threadIdx.x;
  if (tid < NG * 5) s_gt[tid] = labels[(size_t)b * NG * 5 + tid];
  __syncthreads();

  int n = n_fg[b];
  size_t bo = (size_t)b * NAP;
  float li = 0.0f, oe = 0.0f, lc = 0.0f, nf = 0.0f;

  for (int ci = blockIdx.x * 256 + tid; ci < n; ci += gridDim.x * 256) {
    unsigned int m = match_c[bo + ci];
    if (m == 0u) continue;
    int a = fg_list[bo + ci];
    const float* base; int hw, HW, xg, yg; float fs;
    anchor_info(a, p8, p16, p32, b, base, hw, HW, xg, yg, fs);
    float4 pb = bbox_c[bo + ci];
    int mg;
    if (m & (m - 1)) {
      // multi-matched: argmin over ALL g of cost (first-min tie-break)
      unsigned int am = am_c[bo + ci];
      float sl = sl_c[bo + ci];
      float bestc = 3.4e38f; mg = 0;
#pragma unroll 4
      for (int g = 0; g < NG; ++g) {
        float iou = iou_raw(s_gt[g * 5], s_gt[g * 5 + 1], s_gt[g * 5 + 2], s_gt[g * 5 + 3], pb);
        float wv = w_c[((size_t)b * NG + g) * NAP + ci];
        float c = -(wv + sl) - 3.0f * __logf(iou + 1e-8f);
        if (!((am >> g) & 1u)) c += 100000.0f;
        if (c < bestc) { bestc = c; mg = g; }
      }
    } else {
      mg = __ffs(m) - 1;
    }
    float gx = s_gt[mg * 5], gy = s_gt[mg * 5 + 1];
    float gw = s_gt[mg * 5 + 2], gh = s_gt[mg * 5 + 3];
    int cg = (int)s_gt[mg * 5 + 4];
    float piou = iou_raw(gx, gy, gw, gh, pb);
    li += giou_loss(pb, gx, gy, gw, gh);
    float xcls = base[(5 + cg) * HW + hw];
    lc += sb_c[bo + ci] - xcls * piou;   // bce(x,t) = bce(x,0) - x*t
    oe += base[4 * HW + hw];             // obj logit: bce(x,1) = bce(x,0) - x
    nf += 1.0f;
  }

  float vals[4] = {li, oe, lc, nf};
#pragma unroll
  for (int q = 0; q < 4; ++q) {
#pragma unroll
    for (int off = 32; off; off >>= 1) vals[q] += __shfl_down(vals[q], off, 64);
  }
  if ((tid & 63) == 0) {
    int wid = tid >> 6;
    s_red[wid * 4 + 0] = vals[0];
    s_red[wid * 4 + 1] = vals[1];
    s_red[wid * 4 + 2] = vals[2];
    s_red[wid * 4 + 3] = vals[3];
  }
  __syncthreads();
  if (tid < 4) {
    const int slot[4] = {0, 2, 3, 4};
    float s = s_red[tid] + s_red[4 + tid] + s_red[8 + tid] + s_red[12 + tid];
    atomicAdd(&accum[slot[tid]], s);
  }
}

// ---------- kD ----------
__global__ void kD(const float* __restrict__ accum, float* __restrict__ out) {
  float loss_iou = accum[0];
  float loss_obj = accum[1] - accum[2];
  float loss_cls = accum[3];
  float num_fg = fmaxf(accum[4], 1.0f);
  out[0] = (5.0f * loss_iou + loss_obj + loss_cls) / num_fg;
}

// ---------- launch ----------
extern "C" void kernel_launch(void* const* d_in, const int* in_sizes, int n_in,
                              void* d_out, int out_size, void* d_ws, size_t ws_size,
                              hipStream_t stream) {
  const float* p8     = (const float*)d_in[0];
  const float* p16    = (const float*)d_in[1];
  const float* p32    = (const float*)d_in[2];
  const float* labels = (const float*)d_in[3];
  float* out = (float*)d_out;

  const size_t BAP = (size_t)NB * NAP;     // 270336
  char* w = (char*)d_ws;
  float4*       bbox_c  = (float4*)w;                              // 16B-aligned, 17.3 MB
  float*        w_c     = (float*)(w + BAP * 16);                  // NB*NG*NAP*4 = 21.6 MB
  char*         w2      = w + BAP * 16 + (size_t)NB * NG * NAP * 4;
  int*          fg_list = (int*)(w2);
  unsigned int* am_c    = (unsigned int*)(w2 + BAP * 4);
  unsigned int* match_c = (unsigned int*)(w2 + BAP * 8);
  float*        sl_c    = (float*)(w2 + BAP * 12);
  float*        sb_c    = (float*)(w2 + BAP * 16);
  int*          n_fg    = (int*)(w2 + BAP * 20);
  float*        accum   = (float*)(w2 + BAP * 20 + 128);

  hipMemsetAsync(accum, 0, 32, stream);    // match_c zeroed in kA0

  kA0<<<dim3(NB), dim3(1024), 0, stream>>>(p8, p16, p32, labels, am_c, fg_list, n_fg,
                                           match_c, accum);
  kA1<<<dim3(12, NB), dim3(256), 0, stream>>>(p8, p16, p32, labels, fg_list, n_fg,
                                              bbox_c, sl_c, sb_c, w_c);
  kB<<<dim3(NG, NB), dim3(256), 0, stream>>>(labels, bbox_c, sl_c, w_c, am_c, n_fg, match_c);
  kC<<<dim3(12, NB), dim3(256), 0, stream>>>(p8, p16, p32, labels, bbox_c, sl_c, sb_c, w_c,
                                             am_c, fg_list, n_fg, match_c, accum);
  kD<<<1, 1, 0, stream>>>(accum, out);
}

// Round 5
// 182.656 us; speedup vs baseline: 2.5443x; 1.0760x over previous
//
#include <hip/hip_runtime.h>
#include <cstdint>
#include <cstddef>

#define NA 8400   // anchors per image: 80*80 + 40*40 + 20*20
#define NAP 8448  // padded stride (33*256)
#define NB 32     // batch
#define NG 20     // ground truths per image
#define NCL 80    // classes
#define NBLK 33   // 256-thread blocks per image

// ---------- fast math ----------
__device__ __forceinline__ float frcp(float x) { return __builtin_amdgcn_rcpf(x); }
__device__ __forceinline__ float bce0(float x) {
  return fmaxf(x, 0.0f) + __logf(1.0f + __expf(-fabsf(x)));
}

// per-level info (full: pointer + plane)
__device__ __forceinline__ void anchor_info(int a, const float* p8, const float* p16,
                                            const float* p32, int b, const float*& base,
                                            int& hw, int& HW, int& xg, int& yg, float& fs) {
  if (a < 6400)      { hw = a;        HW = 6400; xg = hw % 80; yg = hw / 80; fs = 8.f;
                       base = p8  + (size_t)b * 85 * 6400; }
  else if (a < 8000) { hw = a - 6400; HW = 1600; xg = hw % 40; yg = hw / 40; fs = 16.f;
                       base = p16 + (size_t)b * 85 * 1600; }
  else               { hw = a - 8000; HW = 400;  xg = hw % 20; yg = hw / 20; fs = 32.f;
                       base = p32 + (size_t)b * 85 * 400; }
}

// geometry-only coords (no pointers)
__device__ __forceinline__ void anchor_xy(int a, float& xc, float& yc, float& fs) {
  int xg, yg;
  if (a < 6400)      { xg = a % 80; yg = a / 80; fs = 8.f; }
  else if (a < 8000) { int h = a - 6400; xg = h % 40; yg = h / 40; fs = 16.f; }
  else               { int h = a - 8000; xg = h % 20; yg = h / 20; fs = 32.f; }
  xc = ((float)xg + 0.5f) * fs;
  yc = ((float)yg + 0.5f) * fs;
}

__device__ __forceinline__ float iou_raw(float gx, float gy, float gw, float gh, float4 p) {
  float gtlx = gx - gw * 0.5f, gtly = gy - gh * 0.5f;
  float gbrx = gx + gw * 0.5f, gbry = gy + gh * 0.5f;
  float ptlx = p.x - p.z * 0.5f, ptly = p.y - p.w * 0.5f;
  float pbrx = p.x + p.z * 0.5f, pbry = p.y + p.w * 0.5f;
  float tlx = fmaxf(gtlx, ptlx), tly = fmaxf(gtly, ptly);
  float brx = fminf(gbrx, pbrx), bry = fminf(gbry, pbry);
  float inter = ((tlx < brx) && (tly < bry)) ? (brx - tlx) * (bry - tly) : 0.0f;
  float ag = gw * gh, ap = p.z * p.w;
  return inter * frcp(ag + ap - inter + 1e-16f);
}

__device__ __forceinline__ float giou_loss(float4 bb, float gx, float gy, float gw, float gh) {
  float btlx = bb.x - bb.z * 0.5f, btly = bb.y - bb.w * 0.5f;
  float bbrx = bb.x + bb.z * 0.5f, bbry = bb.y + bb.w * 0.5f;
  float gtlx = gx - gw * 0.5f, gtly = gy - gh * 0.5f;
  float gbrx = gx + gw * 0.5f, gbry = gy + gh * 0.5f;
  float tlx = fmaxf(btlx, gtlx), tly = fmaxf(btly, gtly);
  float brx = fminf(bbrx, gbrx), bry = fminf(bbry, gbry);
  float area_b = bb.z * bb.w, area_g = gw * gh;
  float inter = ((tlx < brx) && (tly < bry)) ? (brx - tlx) * (bry - tly) : 0.0f;
  float uni = area_b + area_g - inter;
  float iou = inter / (uni + 1e-16f);
  float ctlx = fminf(btlx, gtlx), ctly = fminf(btly, gtly);
  float cbrx = fmaxf(bbrx, gbrx), cbry = fmaxf(bbry, gbry);
  float area_c = fmaxf((cbrx - ctlx) * (cbry - ctly), 1e-16f);
  float giou = iou - (area_c - uni) / area_c;
  giou = fminf(fmaxf(giou, -1.0f), 1.0f);
  return 1.0f - giou;
}

__device__ __forceinline__ void block_argmin(float& v, int& i, volatile float* s_v,
                                             volatile int* s_i, int tid) {
#pragma unroll
  for (int off = 32; off; off >>= 1) {
    float ov = __shfl_down(v, off, 64);
    int   oi = __shfl_down(i, off, 64);
    if (ov < v || (ov == v && oi < i)) { v = ov; i = oi; }
  }
  if ((tid & 63) == 0) { s_v[tid >> 6] = v; s_i[tid >> 6] = i; }
  __syncthreads();
  v = s_v[0]; i = s_i[0];
#pragma unroll
  for (int w = 1; w < 4; ++w) {
    float ov = s_v[w]; int oi = s_i[w];
    if (ov < v || (ov == v && oi < i)) { v = ov; i = oi; }
  }
}

// geometry: fg flag + per-GT mask; identical in kG and kX (deterministic)
__device__ __forceinline__ void geom_mask(int a, const float* s_gt, bool& fg,
                                          unsigned int& msk) {
  float xc, yc, fs;
  anchor_xy(a, xc, yc, fs);
  float r = 2.5f * fs;
  fg = false; msk = 0u;
#pragma unroll
  for (int g = 0; g < NG; ++g) {
    float gx = s_gt[g * 4 + 0], gy = s_gt[g * 4 + 1];
    float gw = s_gt[g * 4 + 2], gh = s_gt[g * 4 + 3];
    bool inb = (xc > gx - 0.5f * gw) && (xc < gx + 0.5f * gw) &&
               (yc > gy - 0.5f * gh) && (yc < gy + 0.5f * gh);
    bool inc = (xc > gx - r) && (xc < gx + r) && (yc > gy - r) && (yc < gy + r);
    fg = fg || inb || inc;
    if (inb && inc) msk |= (1u << g);
  }
}

// ---------- kG: wide pass — fg counts per block + obj-BCE sum + match_c zero ----------
__global__ __launch_bounds__(256) void kG(const float* __restrict__ p8,
                                          const float* __restrict__ p16,
                                          const float* __restrict__ p32,
                                          const float* __restrict__ labels,
                                          unsigned int* __restrict__ blk_cnt,
                                          unsigned int* __restrict__ match_c,
                                          float* __restrict__ accum) {
  __shared__ float s_gt[NG * 4];
  __shared__ unsigned int s_wcnt[4];
  __shared__ float s_part[4];
  int blk = blockIdx.x, b = blockIdx.y, tid = threadIdx.x, lane = tid & 63, wid = tid >> 6;
  if (tid < NG) {
    s_gt[tid * 4 + 0] = labels[((size_t)b * NG + tid) * 5 + 0];
    s_gt[tid * 4 + 1] = labels[((size_t)b * NG + tid) * 5 + 1];
    s_gt[tid * 4 + 2] = labels[((size_t)b * NG + tid) * 5 + 2];
    s_gt[tid * 4 + 3] = labels[((size_t)b * NG + tid) * 5 + 3];
  }
  __syncthreads();

  int a = blk * 256 + tid;
  match_c[(size_t)b * NAP + a] = 0u;
  bool fg = false;
  unsigned int msk;
  float bce_obj = 0.0f;
  if (a < NA) {
    const float* base; int hw, HW, xg, yg; float fs;
    anchor_info(a, p8, p16, p32, b, base, hw, HW, xg, yg, fs);
    bce_obj = bce0(base[4 * HW + hw]);     // coalesced obj-plane stream
    geom_mask(a, s_gt, fg, msk);
  }
  unsigned long long bm = __ballot(fg);
#pragma unroll
  for (int off = 32; off; off >>= 1) bce_obj += __shfl_down(bce_obj, off, 64);
  if (lane == 0) { s_wcnt[wid] = (unsigned int)__popcll(bm); s_part[wid] = bce_obj; }
  __syncthreads();
  if (tid == 0) {
    blk_cnt[b * NBLK + blk] = s_wcnt[0] + s_wcnt[1] + s_wcnt[2] + s_wcnt[3];
    atomicAdd(&accum[1], s_part[0] + s_part[1] + s_part[2] + s_part[3]);
  }
}

// ---------- kX: wide ordered scatter — shuffle prefix-scan of blk counts ----------
__global__ __launch_bounds__(256) void kX(const float* __restrict__ labels,
                                          const unsigned int* __restrict__ blk_cnt,
                                          int* __restrict__ fg_list,
                                          unsigned int* __restrict__ am_c,
                                          int* __restrict__ n_fg) {
  __shared__ float s_gt[NG * 4];
  __shared__ unsigned int s_wcnt[4];
  __shared__ unsigned int s_base;
  int blk = blockIdx.x, b = blockIdx.y, tid = threadIdx.x, lane = tid & 63, wid = tid >> 6;
  if (tid < NG) {
    s_gt[tid * 4 + 0] = labels[((size_t)b * NG + tid) * 5 + 0];
    s_gt[tid * 4 + 1] = labels[((size_t)b * NG + tid) * 5 + 1];
    s_gt[tid * 4 + 2] = labels[((size_t)b * NG + tid) * 5 + 2];
    s_gt[tid * 4 + 3] = labels[((size_t)b * NG + tid) * 5 + 3];
  }
  if (wid == 0) {                          // 64-lane shuffle prefix over 33 counts
    unsigned int c = (lane < NBLK) ? blk_cnt[b * NBLK + lane] : 0u;
    unsigned int p = c;
#pragma unroll
    for (int off = 1; off < 64; off <<= 1) {
      unsigned int t = __shfl_up(p, off, 64);
      if (lane >= off) p += t;
    }
    if (lane == (unsigned)blk) s_base = p - c;        // exclusive prefix for this block
    if (blk == 0 && lane == NBLK - 1) n_fg[b] = (int)p;  // total
  }
  __syncthreads();

  int a = blk * 256 + tid;
  bool fg = false;
  unsigned int msk = 0u;
  if (a < NA) geom_mask(a, s_gt, fg, msk);
  unsigned long long bm = __ballot(fg);
  if (lane == 0) s_wcnt[wid] = (unsigned int)__popcll(bm);
  __syncthreads();
  if (fg) {
    unsigned int pos = s_base;
    for (int w = 0; w < wid; ++w) pos += s_wcnt[w];
    pos += (unsigned int)__popcll(bm & ((1ull << lane) - 1ull));
    fg_list[(size_t)b * NAP + pos] = a;
    am_c[(size_t)b * NAP + pos] = msk | 0x80000000u;
  }
}

// ---------- kA1: heavy per-fg-anchor pass (balanced over compacted list) ----------
__global__ __launch_bounds__(256) void kA1(const float* __restrict__ p8,
                                           const float* __restrict__ p16,
                                           const float* __restrict__ p32,
                                           const float* __restrict__ labels,
                                           const int* __restrict__ fg_list,
                                           const int* __restrict__ n_fg,
                                           float4* __restrict__ bbox_c,
                                           float* __restrict__ sl_c,
                                           float* __restrict__ sb_c,
                                           float* __restrict__ w_c) {
  __shared__ unsigned int s_gmask[NCL];   // class -> bitmap of g's with that class
  int b = blockIdx.y, tid = threadIdx.x;
  if (tid < NCL) s_gmask[tid] = 0u;
  __syncthreads();
  if (tid < NG) {
    int c = (int)labels[((size_t)b * NG + tid) * 5 + 4];
    atomicOr(&s_gmask[c], 1u << tid);
  }
  __syncthreads();

  int n = n_fg[b];
  for (int ci = blockIdx.x * 256 + tid; ci < n; ci += gridDim.x * 256) {
    int a = fg_list[(size_t)b * NAP + ci];
    const float* base; int hw, HW, xg, yg; float fs;
    anchor_info(a, p8, p16, p32, b, base, hw, HW, xg, yg, fs);

    float obj = base[4 * HW + hw];
    float v0 = base[hw];
    float v1 = base[HW + hw];
    float v2 = base[2 * HW + hw];
    float v3 = base[3 * HW + hw];
    bbox_c[(size_t)b * NAP + ci] = make_float4((v0 + (float)xg) * fs, (v1 + (float)yg) * fs,
                                               __expf(v2) * fs, __expf(v3) * fs);
    // log(sigmoid(obj)) = min(obj,0) - log(1+exp(-|obj|))
    float uo  = __logf(1.0f + __expf(-fabsf(obj)));
    float lso = fminf(obj, 0.0f) - uo;

    float sl = 0.0f, sb = 0.0f;
    for (int cc = 0; cc < NCL; cc += 8) {
      float xs[8];
#pragma unroll
      for (int j = 0; j < 8; ++j) xs[j] = base[(5 + cc + j) * HW + hw];
#pragma unroll
      for (int j = 0; j < 8; ++j) {
        float x = xs[j];
        float u = __logf(1.0f + __expf(-fabsf(x)));
        sb += fmaxf(x, 0.0f) + u;                 // bce(x,0)
        float lsx = fminf(x, 0.0f) - u;           // log(sigmoid(x))
        float lpr = 0.5f * (lsx + lso);           // log p  (p = sqrt(sx*so))
        float p   = __expf(lpr);
        float l1p = fmaxf(__logf(1.0f - p), -100.0f);
        sl += l1p;
        unsigned int m = s_gmask[cc + j];
        if (m) {                                  // wave-uniform branch
          float w = fmaxf(lpr, -100.0f) - l1p;    // lp - l1p
          do {
            int g = __ffs(m) - 1; m &= m - 1;
            w_c[((size_t)b * NG + g) * NAP + ci] = w;
          } while (m);
        }
      }
    }
    sl_c[(size_t)b * NAP + ci] = sl;
    sb_c[(size_t)b * NAP + ci] = sb;
  }
}

// ---------- kB: per (b,g) cost row over COMPACTED candidates + dyn_k top-k ----------
__global__ __launch_bounds__(256) void kB(const float* __restrict__ labels,
                                          const float4* __restrict__ bbox_c,
                                          const float* __restrict__ sl_c,
                                          const float* __restrict__ w_c,
                                          const unsigned int* __restrict__ am_c,
                                          const int* __restrict__ n_fg,
                                          unsigned int* __restrict__ match_c) {
  __shared__ float s_cost[NAP];   // 33 KB (only n used)
  __shared__ float s_wt[4 * 10];
  __shared__ float s_v[4];
  __shared__ int   s_i[4];
  __shared__ int   s_k;

  int g = blockIdx.x, b = blockIdx.y, tid = threadIdx.x;
  int lane = tid & 63, wid = tid >> 6;
  int n = n_fg[b];
  size_t bo = (size_t)b * NAP;
  const float* __restrict__ wg = w_c + ((size_t)b * NG + g) * NAP;

  float gx = labels[((size_t)b * NG + g) * 5 + 0];
  float gy = labels[((size_t)b * NG + g) * 5 + 1];
  float gw = labels[((size_t)b * NG + g) * 5 + 2];
  float gh = labels[((size_t)b * NG + g) * 5 + 3];

  float t10[10];
#pragma unroll
  for (int j = 0; j < 10; ++j) t10[j] = 0.0f;

  for (int ci = tid; ci < n; ci += 256) {
    unsigned int am = am_c[bo + ci];
    float wv = wg[ci];
    float sl = sl_c[bo + ci];
    float4 pb = bbox_c[bo + ci];
    float iou = iou_raw(gx, gy, gw, gh, pb);
    if (iou > t10[9]) {
      t10[9] = iou;
#pragma unroll
      for (int q = 9; q > 0; --q) {
        if (t10[q] > t10[q - 1]) { float t = t10[q]; t10[q] = t10[q - 1]; t10[q - 1] = t; }
        else break;
      }
    }
    float c = -(wv + sl) - 3.0f * __logf(iou + 1e-8f);
    if (!((am >> g) & 1u)) c += 100000.0f;
    s_cost[ci] = c;
  }

  // per-wave top-10 extraction (regs+shuffles, no syncs), then 4-list merge
  for (int r = 0; r < 10; ++r) {
    float v = t10[0];
    float bv = v;
#pragma unroll
    for (int off = 32; off; off >>= 1) bv = fmaxf(bv, __shfl_down(bv, off, 64));
    bv = __shfl(bv, 0, 64);
    unsigned long long won = __ballot(v == bv);
    if (lane == __ffsll(won) - 1) {
#pragma unroll
      for (int q = 0; q < 9; ++q) t10[q] = t10[q + 1];
      t10[9] = -1.0f;
    }
    if (lane == 0) s_wt[wid * 10 + r] = bv;
  }
  __syncthreads();

  if (tid == 0) {
    int p0 = 0, p1 = 0, p2 = 0, p3 = 0;
    float s = 0.0f;
    for (int r = 0; r < 10; ++r) {
      float v0 = (p0 < 10) ? s_wt[p0]      : -2.0f;
      float v1 = (p1 < 10) ? s_wt[10 + p1] : -2.0f;
      float v2 = (p2 < 10) ? s_wt[20 + p2] : -2.0f;
      float v3 = (p3 < 10) ? s_wt[30 + p3] : -2.0f;
      float m = fmaxf(fmaxf(v0, v1), fmaxf(v2, v3));
      s += m;
      if (m == v0) ++p0; else if (m == v1) ++p1; else if (m == v2) ++p2; else ++p3;
    }
    int k = (int)s;                 // truncation matches astype(int32)
    if (k < 1) k = 1;
    s_k = k;
  }
  __syncthreads();
  int k = s_k;

  // extract k smallest; (cost, ci) lexicographic == stable argsort (ci order == anchor order)
  for (int it = 0; it < k; ++it) {
    float bv = 3.4e38f; int bi = NAP;
    for (int ci = tid; ci < n; ci += 256) {
      float v = s_cost[ci];
      if (v < bv || (v == bv && ci < bi)) { bv = v; bi = ci; }
    }
    block_argmin(bv, bi, s_v, s_i, tid);
    if (bv >= 1e8f) break;          // exhausted real candidates (cost <= ~1.1e5)
    if (tid == 0) {
      atomicOr(&match_c[bo + bi], 1u << g);
      s_cost[bi] = 3.4e38f;
    }
    __syncthreads();
  }
}

// ---------- kC: finalize matched anchors (compacted) ----------
__global__ __launch_bounds__(256) void kC(const float* __restrict__ p8,
                                          const float* __restrict__ p16,
                                          const float* __restrict__ p32,
                                          const float* __restrict__ labels,
                                          const float4* __restrict__ bbox_c,
                                          const float* __restrict__ sl_c,
                                          const float* __restrict__ sb_c,
                                          const float* __restrict__ w_c,
                                          const unsigned int* __restrict__ am_c,
                                          const int* __restrict__ fg_list,
                                          const int* __restrict__ n_fg,
                                          const unsigned int* __restrict__ match_c,
                                          float* __restrict__ accum) {
  __shared__ float s_gt[NG * 5];
  __shared__ float s_red[16];
  int b = blockIdx.y, tid = threadIdx.x;
  if (tid < NG * 5) s_gt[tid] = labels[(size_t)b * NG * 5 + tid];
  __syncthreads();

  int n = n_fg[b];
  size_t bo = (size_t)b * NAP;
  float li = 0.0f, oe = 0.0f, lc = 0.0f, nf = 0.0f;

  for (int ci = blockIdx.x * 256 + tid; ci < n; ci += gridDim.x * 256) {
    unsigned int m = match_c[bo + ci];
    if (m == 0u) continue;
    int a = fg_list[bo + ci];
    const float* base; int hw, HW, xg, yg; float fs;
    anchor_info(a, p8, p16, p32, b, base, hw, HW, xg, yg, fs);
    float4 pb = bbox_c[bo + ci];
    int mg;
    if (m & (m - 1)) {
      // multi-matched: argmin over ALL g of cost (first-min tie-break)
      unsigned int am = am_c[bo + ci];
      float sl = sl_c[bo + ci];
      float bestc = 3.4e38f; mg = 0;
#pragma unroll 4
      for (int g = 0; g < NG; ++g) {
        float iou = iou_raw(s_gt[g * 5], s_gt[g * 5 + 1], s_gt[g * 5 + 2], s_gt[g * 5 + 3], pb);
        float wv = w_c[((size_t)b * NG + g) * NAP + ci];
        float c = -(wv + sl) - 3.0f * __logf(iou + 1e-8f);
        if (!((am >> g) & 1u)) c += 100000.0f;
        if (c < bestc) { bestc = c; mg = g; }
      }
    } else {
      mg = __ffs(m) - 1;
    }
    float gx = s_gt[mg * 5], gy = s_gt[mg * 5 + 1];
    float gw = s_gt[mg * 5 + 2], gh = s_gt[mg * 5 + 3];
    int cg = (int)s_gt[mg * 5 + 4];
    float piou = iou_raw(gx, gy, gw, gh, pb);
    li += giou_loss(pb, gx, gy, gw, gh);
    float xcls = base[(5 + cg) * HW + hw];
    lc += sb_c[bo + ci] - xcls * piou;   // bce(x,t) = bce(x,0) - x*t
    oe += base[4 * HW + hw];             // obj logit: bce(x,1) = bce(x,0) - x
    nf += 1.0f;
  }

  float vals[4] = {li, oe, lc, nf};
#pragma unroll
  for (int q = 0; q < 4; ++q) {
#pragma unroll
    for (int off = 32; off; off >>= 1) vals[q] += __shfl_down(vals[q], off, 64);
  }
  if ((tid & 63) == 0) {
    int wid = tid >> 6;
    s_red[wid * 4 + 0] = vals[0];
    s_red[wid * 4 + 1] = vals[1];
    s_red[wid * 4 + 2] = vals[2];
    s_red[wid * 4 + 3] = vals[3];
  }
  __syncthreads();
  if (tid < 4) {
    const int slot[4] = {0, 2, 3, 4};
    float s = s_red[tid] + s_red[4 + tid] + s_red[8 + tid] + s_red[12 + tid];
    atomicAdd(&accum[slot[tid]], s);
  }
}

// ---------- kD ----------
__global__ void kD(const float* __restrict__ accum, float* __restrict__ out) {
  float loss_iou = accum[0];
  float loss_obj = accum[1] - accum[2];
  float loss_cls = accum[3];
  float num_fg = fmaxf(accum[4], 1.0f);
  out[0] = (5.0f * loss_iou + loss_obj + loss_cls) / num_fg;
}

// ---------- launch ----------
extern "C" void kernel_launch(void* const* d_in, const int* in_sizes, int n_in,
                              void* d_out, int out_size, void* d_ws, size_t ws_size,
                              hipStream_t stream) {
  const float* p8     = (const float*)d_in[0];
  const float* p16    = (const float*)d_in[1];
  const float* p32    = (const float*)d_in[2];
  const float* labels = (const float*)d_in[3];
  float* out = (float*)d_out;

  const size_t BAP = (size_t)NB * NAP;     // 270336
  char* w = (char*)d_ws;
  float4*       bbox_c  = (float4*)w;                              // 16B-aligned, 17.3 MB
  float*        w_c     = (float*)(w + BAP * 16);                  // NB*NG*NAP*4 = 21.6 MB
  char*         w2      = w + BAP * 16 + (size_t)NB * NG * NAP * 4;
  int*          fg_list = (int*)(w2);
  unsigned int* am_c    = (unsigned int*)(w2 + BAP * 4);
  unsigned int* match_c = (unsigned int*)(w2 + BAP * 8);
  float*        sl_c    = (float*)(w2 + BAP * 12);
  float*        sb_c    = (float*)(w2 + BAP * 16);
  int*          n_fg    = (int*)(w2 + BAP * 20);
  float*        accum   = (float*)(w2 + BAP * 20 + 128);
  unsigned int* blk_cnt = (unsigned int*)(w2 + BAP * 20 + 256);    // NB*NBLK u32

  hipMemsetAsync(accum, 0, 32, stream);    // match_c zeroed in kG

  kG<<<dim3(NBLK, NB), dim3(256), 0, stream>>>(p8, p16, p32, labels, blk_cnt, match_c, accum);
  kX<<<dim3(NBLK, NB), dim3(256), 0, stream>>>(labels, blk_cnt, fg_list, am_c, n_fg);
  kA1<<<dim3(12, NB), dim3(256), 0, stream>>>(p8, p16, p32, labels, fg_list, n_fg,
                                              bbox_c, sl_c, sb_c, w_c);
  kB<<<dim3(NG, NB), dim3(256), 0, stream>>>(labels, bbox_c, sl_c, w_c, am_c, n_fg, match_c);
  kC<<<dim3(12, NB), dim3(256), 0, stream>>>(p8, p16, p32, labels, bbox_c, sl_c, sb_c, w_c,
                                             am_c, fg_list, n_fg, match_c, accum);
  kD<<<1, 1, 0, stream>>>(accum, out);
}

// Round 6
// 181.671 us; speedup vs baseline: 2.5581x; 1.0054x over previous
//
#include <hip/hip_runtime.h>
#include <cstdint>
#include <cstddef>

#define NA 8400   // anchors per image: 80*80 + 40*40 + 20*20
#define NAP 8448  // padded stride (33*256)
#define NB 32     // batch
#define NG 20     // ground truths per image
#define NCL 80    // classes
#define NBLK 33   // 256-thread blocks per image
#define KC_BLKS 12

// ---------- fast math ----------
__device__ __forceinline__ float frcp(float x) { return __builtin_amdgcn_rcpf(x); }
__device__ __forceinline__ float bce0(float x) {
  return fmaxf(x, 0.0f) + __logf(1.0f + __expf(-fabsf(x)));
}

__device__ __forceinline__ void anchor_info(int a, const float* p8, const float* p16,
                                            const float* p32, int b, const float*& base,
                                            int& hw, int& HW, int& xg, int& yg, float& fs) {
  if (a < 6400)      { hw = a;        HW = 6400; xg = hw % 80; yg = hw / 80; fs = 8.f;
                       base = p8  + (size_t)b * 85 * 6400; }
  else if (a < 8000) { hw = a - 6400; HW = 1600; xg = hw % 40; yg = hw / 40; fs = 16.f;
                       base = p16 + (size_t)b * 85 * 1600; }
  else               { hw = a - 8000; HW = 400;  xg = hw % 20; yg = hw / 20; fs = 32.f;
                       base = p32 + (size_t)b * 85 * 400; }
}

__device__ __forceinline__ float iou_raw(float gx, float gy, float gw, float gh, float4 p) {
  float gtlx = gx - gw * 0.5f, gtly = gy - gh * 0.5f;
  float gbrx = gx + gw * 0.5f, gbry = gy + gh * 0.5f;
  float ptlx = p.x - p.z * 0.5f, ptly = p.y - p.w * 0.5f;
  float pbrx = p.x + p.z * 0.5f, pbry = p.y + p.w * 0.5f;
  float tlx = fmaxf(gtlx, ptlx), tly = fmaxf(gtly, ptly);
  float brx = fminf(gbrx, pbrx), bry = fminf(gbry, pbry);
  float inter = ((tlx < brx) && (tly < bry)) ? (brx - tlx) * (bry - tly) : 0.0f;
  float ag = gw * gh, ap = p.z * p.w;
  return inter * frcp(ag + ap - inter + 1e-16f);
}

__device__ __forceinline__ float giou_loss(float4 bb, float gx, float gy, float gw, float gh) {
  float btlx = bb.x - bb.z * 0.5f, btly = bb.y - bb.w * 0.5f;
  float bbrx = bb.x + bb.z * 0.5f, bbry = bb.y + bb.w * 0.5f;
  float gtlx = gx - gw * 0.5f, gtly = gy - gh * 0.5f;
  float gbrx = gx + gw * 0.5f, gbry = gy + gh * 0.5f;
  float tlx = fmaxf(btlx, gtlx), tly = fmaxf(btly, gtly);
  float brx = fminf(bbrx, gbrx), bry = fminf(bbry, gbry);
  float area_b = bb.z * bb.w, area_g = gw * gh;
  float inter = ((tlx < brx) && (tly < bry)) ? (brx - tlx) * (bry - tly) : 0.0f;
  float uni = area_b + area_g - inter;
  float iou = inter / (uni + 1e-16f);
  float ctlx = fminf(btlx, gtlx), ctly = fminf(btly, gtly);
  float cbrx = fmaxf(bbrx, gbrx), cbry = fmaxf(bbry, gbry);
  float area_c = fmaxf((cbrx - ctlx) * (cbry - ctly), 1e-16f);
  float giou = iou - (area_c - uni) / area_c;
  giou = fminf(fmaxf(giou, -1.0f), 1.0f);
  return 1.0f - giou;
}

__device__ __forceinline__ void block_argmin(float& v, int& i, volatile float* s_v,
                                             volatile int* s_i, int tid) {
#pragma unroll
  for (int off = 32; off; off >>= 1) {
    float ov = __shfl_down(v, off, 64);
    int   oi = __shfl_down(i, off, 64);
    if (ov < v || (ov == v && oi < i)) { v = ov; i = oi; }
  }
  if ((tid & 63) == 0) { s_v[tid >> 6] = v; s_i[tid >> 6] = i; }
  __syncthreads();
  v = s_v[0]; i = s_i[0];
#pragma unroll
  for (int w = 1; w < 4; ++w) {
    float ov = s_v[w]; int oi = s_i[w];
    if (ov < v || (ov == v && oi < i)) { v = ov; i = oi; }
  }
}

// ---------- kGXA: geometry + atomic compaction + heavy per-fg-anchor pass (fused) ----------
__global__ __launch_bounds__(256) void kGXA(const float* __restrict__ p8,
                                            const float* __restrict__ p16,
                                            const float* __restrict__ p32,
                                            const float* __restrict__ labels,
                                            int* __restrict__ n_fg_cnt,
                                            int* __restrict__ fg_list,
                                            unsigned int* __restrict__ am_c,
                                            float4* __restrict__ bbox_c,
                                            float* __restrict__ sl_c,
                                            float* __restrict__ sb_c,
                                            float* __restrict__ w_c,
                                            unsigned int* __restrict__ match_c,
                                            float* __restrict__ blk_obj) {
  __shared__ float s_gt[NG * 4];
  __shared__ unsigned int s_gmask[NCL];
  __shared__ unsigned int s_wcnt[4];
  __shared__ float s_part[4];
  __shared__ unsigned int s_base;
  int blk = blockIdx.x, b = blockIdx.y, tid = threadIdx.x, lane = tid & 63, wid = tid >> 6;

  if (tid < NCL) s_gmask[tid] = 0u;
  if (tid < NG) {
    s_gt[tid * 4 + 0] = labels[((size_t)b * NG + tid) * 5 + 0];
    s_gt[tid * 4 + 1] = labels[((size_t)b * NG + tid) * 5 + 1];
    s_gt[tid * 4 + 2] = labels[((size_t)b * NG + tid) * 5 + 2];
    s_gt[tid * 4 + 3] = labels[((size_t)b * NG + tid) * 5 + 3];
  }
  __syncthreads();
  if (tid < NG) {
    int c = (int)labels[((size_t)b * NG + tid) * 5 + 4];
    atomicOr(&s_gmask[c], 1u << tid);
  }
  __syncthreads();

  int a = blk * 256 + tid;
  match_c[(size_t)b * NAP + a] = 0u;     // NBLK*256 == NAP: full coverage

  bool fg = false;
  unsigned int msk = 0u;
  float bce_obj = 0.0f, obj = 0.0f;
  const float* base = nullptr; int hw = 0, HW = 0, xg = 0, yg = 0; float fs = 8.f;
  if (a < NA) {
    anchor_info(a, p8, p16, p32, b, base, hw, HW, xg, yg, fs);
    obj = base[4 * HW + hw];             // coalesced obj-plane stream
    bce_obj = bce0(obj);
    float xc = ((float)xg + 0.5f) * fs;
    float yc = ((float)yg + 0.5f) * fs;
    float r = 2.5f * fs;
#pragma unroll
    for (int g = 0; g < NG; ++g) {
      float gx = s_gt[g * 4 + 0], gy = s_gt[g * 4 + 1];
      float gw = s_gt[g * 4 + 2], gh = s_gt[g * 4 + 3];
      bool inb = (xc > gx - 0.5f * gw) && (xc < gx + 0.5f * gw) &&
                 (yc > gy - 0.5f * gh) && (yc < gy + 0.5f * gh);
      bool inc = (xc > gx - r) && (xc < gx + r) && (yc > gy - r) && (yc < gy + r);
      fg = fg || inb || inc;
      if (inb && inc) msk |= (1u << g);
    }
  }

  unsigned long long bm = __ballot(fg);
#pragma unroll
  for (int off = 32; off; off >>= 1) bce_obj += __shfl_down(bce_obj, off, 64);
  if (lane == 0) { s_wcnt[wid] = (unsigned int)__popcll(bm); s_part[wid] = bce_obj; }
  __syncthreads();
  if (tid == 0) {
    unsigned int cnt = s_wcnt[0] + s_wcnt[1] + s_wcnt[2] + s_wcnt[3];
    s_base = cnt ? (unsigned int)atomicAdd(&n_fg_cnt[b], (int)cnt) : 0u;
    blk_obj[b * NBLK + blk] = s_part[0] + s_part[1] + s_part[2] + s_part[3];
  }
  __syncthreads();

  if (!fg) return;
  unsigned int pos = s_base;
  for (int w = 0; w < wid; ++w) pos += s_wcnt[w];
  pos += (unsigned int)__popcll(bm & ((1ull << lane) - 1ull));
  int ci = (int)pos;
  size_t bo = (size_t)b * NAP;
  fg_list[bo + ci] = a;
  am_c[bo + ci] = msk | 0x80000000u;

  // heavy per-anchor work (1 anchor/thread; fg waves are clustered so divergence waste is low)
  float v0 = base[hw];
  float v1 = base[HW + hw];
  float v2 = base[2 * HW + hw];
  float v3 = base[3 * HW + hw];
  bbox_c[bo + ci] = make_float4((v0 + (float)xg) * fs, (v1 + (float)yg) * fs,
                                __expf(v2) * fs, __expf(v3) * fs);
  // log(sigmoid(obj)) = min(obj,0) - log(1+exp(-|obj|))
  float uo  = __logf(1.0f + __expf(-fabsf(obj)));
  float lso = fminf(obj, 0.0f) - uo;

  float sl = 0.0f, sb = 0.0f;
  for (int cc = 0; cc < NCL; cc += 8) {
    float xs[8];
#pragma unroll
    for (int j = 0; j < 8; ++j) xs[j] = base[(5 + cc + j) * HW + hw];
#pragma unroll
    for (int j = 0; j < 8; ++j) {
      float x = xs[j];
      float u = __logf(1.0f + __expf(-fabsf(x)));
      sb += fmaxf(x, 0.0f) + u;                 // bce(x,0)
      float lsx = fminf(x, 0.0f) - u;           // log(sigmoid(x))
      float lpr = 0.5f * (lsx + lso);           // log p  (p = sqrt(sx*so))
      float p   = __expf(lpr);
      float l1p = fmaxf(__logf(1.0f - p), -100.0f);
      sl += l1p;
      unsigned int m = s_gmask[cc + j];
      if (m) {                                  // wave-uniform branch
        float w = fmaxf(lpr, -100.0f) - l1p;    // lp - l1p
        do {
          int g = __ffs(m) - 1; m &= m - 1;
          w_c[((size_t)b * NG + g) * NAP + ci] = w;
        } while (m);
      }
    }
  }
  sl_c[bo + ci] = sl;
  sb_c[bo + ci] = sb;
}

// ---------- kB: per (b,g) cost row over compacted candidates + dyn_k top-k ----------
__global__ __launch_bounds__(256) void kB(const float* __restrict__ labels,
                                          const float4* __restrict__ bbox_c,
                                          const float* __restrict__ sl_c,
                                          const float* __restrict__ w_c,
                                          const unsigned int* __restrict__ am_c,
                                          const int* __restrict__ n_fg,
                                          unsigned int* __restrict__ match_c) {
  __shared__ float s_cost[NAP];   // 33 KB (only n used)
  __shared__ float s_wt[4 * 10];
  __shared__ float s_v[4];
  __shared__ int   s_i[4];
  __shared__ int   s_k;

  int g = blockIdx.x, b = blockIdx.y, tid = threadIdx.x;
  int lane = tid & 63, wid = tid >> 6;
  int n = n_fg[b];
  size_t bo = (size_t)b * NAP;
  const float* __restrict__ wg = w_c + ((size_t)b * NG + g) * NAP;

  float gx = labels[((size_t)b * NG + g) * 5 + 0];
  float gy = labels[((size_t)b * NG + g) * 5 + 1];
  float gw = labels[((size_t)b * NG + g) * 5 + 2];
  float gh = labels[((size_t)b * NG + g) * 5 + 3];

  float t10[10];
#pragma unroll
  for (int j = 0; j < 10; ++j) t10[j] = 0.0f;

  for (int ci = tid; ci < n; ci += 256) {
    unsigned int am = am_c[bo + ci];
    float wv = wg[ci];
    float sl = sl_c[bo + ci];
    float4 pb = bbox_c[bo + ci];
    float iou = iou_raw(gx, gy, gw, gh, pb);
    if (iou > t10[9]) {
      t10[9] = iou;
#pragma unroll
      for (int q = 9; q > 0; --q) {
        if (t10[q] > t10[q - 1]) { float t = t10[q]; t10[q] = t10[q - 1]; t10[q - 1] = t; }
        else break;
      }
    }
    float c = -(wv + sl) - 3.0f * __logf(iou + 1e-8f);
    if (!((am >> g) & 1u)) c += 100000.0f;
    s_cost[ci] = c;
  }

  // per-wave top-10 extraction (regs+shuffles, no syncs), then 4-list merge
  for (int r = 0; r < 10; ++r) {
    float v = t10[0];
    float bv = v;
#pragma unroll
    for (int off = 32; off; off >>= 1) bv = fmaxf(bv, __shfl_down(bv, off, 64));
    bv = __shfl(bv, 0, 64);
    unsigned long long won = __ballot(v == bv);
    if (lane == __ffsll(won) - 1) {
#pragma unroll
      for (int q = 0; q < 9; ++q) t10[q] = t10[q + 1];
      t10[9] = -1.0f;
    }
    if (lane == 0) s_wt[wid * 10 + r] = bv;
  }
  __syncthreads();

  if (tid == 0) {
    int p0 = 0, p1 = 0, p2 = 0, p3 = 0;
    float s = 0.0f;
    for (int r = 0; r < 10; ++r) {
      float v0 = (p0 < 10) ? s_wt[p0]      : -2.0f;
      float v1 = (p1 < 10) ? s_wt[10 + p1] : -2.0f;
      float v2 = (p2 < 10) ? s_wt[20 + p2] : -2.0f;
      float v3 = (p3 < 10) ? s_wt[30 + p3] : -2.0f;
      float m = fmaxf(fmaxf(v0, v1), fmaxf(v2, v3));
      s += m;
      if (m == v0) ++p0; else if (m == v1) ++p1; else if (m == v2) ++p2; else ++p3;
    }
    int k = (int)s;                 // truncation matches astype(int32)
    if (k < 1) k = 1;
    s_k = k;
  }
  __syncthreads();
  int k = s_k;

  // extract k smallest; ties effectively never occur (continuous costs)
  for (int it = 0; it < k; ++it) {
    float bv = 3.4e38f; int bi = NAP;
    for (int ci = tid; ci < n; ci += 256) {
      float v = s_cost[ci];
      if (v < bv || (v == bv && ci < bi)) { bv = v; bi = ci; }
    }
    block_argmin(bv, bi, s_v, s_i, tid);
    if (bv >= 1e8f) break;          // exhausted real candidates (cost <= ~1.1e5)
    if (tid == 0) {
      atomicOr(&match_c[bo + bi], 1u << g);
      s_cost[bi] = 3.4e38f;
    }
    __syncthreads();
  }
}

// ---------- kCD: finalize matched anchors + last-block scalar epilogue ----------
__global__ __launch_bounds__(256) void kCD(const float* __restrict__ p8,
                                           const float* __restrict__ p16,
                                           const float* __restrict__ p32,
                                           const float* __restrict__ labels,
                                           const float4* __restrict__ bbox_c,
                                           const float* __restrict__ sl_c,
                                           const float* __restrict__ sb_c,
                                           const float* __restrict__ w_c,
                                           const unsigned int* __restrict__ am_c,
                                           const int* __restrict__ fg_list,
                                           const int* __restrict__ n_fg,
                                           const unsigned int* __restrict__ match_c,
                                           const float* __restrict__ blk_obj,
                                           float* __restrict__ accum,
                                           int* __restrict__ done_cnt,
                                           float* __restrict__ out) {
  __shared__ float s_gt[NG * 5];
  __shared__ float s_red[16];
  __shared__ int s_last;
  int b = blockIdx.y, tid = threadIdx.x;
  if (tid < NG * 5) s_gt[tid] = labels[(size_t)b * NG * 5 + tid];
  __syncthreads();

  int n = n_fg[b];
  size_t bo = (size_t)b * NAP;
  float li = 0.0f, oe = 0.0f, lc = 0.0f, nf = 0.0f;

  for (int ci = blockIdx.x * 256 + tid; ci < n; ci += KC_BLKS * 256) {
    unsigned int m = match_c[bo + ci];
    if (m == 0u) continue;
    int a = fg_list[bo + ci];
    const float* base; int hw, HW, xg, yg; float fs;
    anchor_info(a, p8, p16, p32, b, base, hw, HW, xg, yg, fs);
    float4 pb = bbox_c[bo + ci];
    int mg;
    if (m & (m - 1)) {
      // multi-matched: argmin over ALL g of cost (first-min tie-break)
      unsigned int am = am_c[bo + ci];
      float sl = sl_c[bo + ci];
      float bestc = 3.4e38f; mg = 0;
#pragma unroll 4
      for (int g = 0; g < NG; ++g) {
        float iou = iou_raw(s_gt[g * 5], s_gt[g * 5 + 1], s_gt[g * 5 + 2], s_gt[g * 5 + 3], pb);
        float wv = w_c[((size_t)b * NG + g) * NAP + ci];
        float c = -(wv + sl) - 3.0f * __logf(iou + 1e-8f);
        if (!((am >> g) & 1u)) c += 100000.0f;
        if (c < bestc) { bestc = c; mg = g; }
      }
    } else {
      mg = __ffs(m) - 1;
    }
    float gx = s_gt[mg * 5], gy = s_gt[mg * 5 + 1];
    float gw = s_gt[mg * 5 + 2], gh = s_gt[mg * 5 + 3];
    int cg = (int)s_gt[mg * 5 + 4];
    float piou = iou_raw(gx, gy, gw, gh, pb);
    li += giou_loss(pb, gx, gy, gw, gh);
    float xcls = base[(5 + cg) * HW + hw];
    lc += sb_c[bo + ci] - xcls * piou;   // bce(x,t) = bce(x,0) - x*t
    oe += base[4 * HW + hw];             // obj logit: bce(x,1) = bce(x,0) - x
    nf += 1.0f;
  }

  float vals[4] = {li, oe, lc, nf};
#pragma unroll
  for (int q = 0; q < 4; ++q) {
#pragma unroll
    for (int off = 32; off; off >>= 1) vals[q] += __shfl_down(vals[q], off, 64);
  }
  if ((tid & 63) == 0) {
    int wid = tid >> 6;
    s_red[wid * 4 + 0] = vals[0];
    s_red[wid * 4 + 1] = vals[1];
    s_red[wid * 4 + 2] = vals[2];
    s_red[wid * 4 + 3] = vals[3];
  }
  __syncthreads();
  if (tid < 4) {
    const int slot[4] = {0, 2, 3, 4};
    float s = s_red[tid] + s_red[4 + tid] + s_red[8 + tid] + s_red[12 + tid];
    atomicAdd(&accum[slot[tid]], s);
  }

  // done-ticket: last block computes the scalar output
  if (tid == 0) {
    __threadfence();
    int old = atomicAdd(done_cnt, 1);
    s_last = (old == KC_BLKS * NB - 1) ? 1 : 0;
  }
  __syncthreads();
  if (s_last) {
    float s = 0.0f;
    for (int i = tid; i < NB * NBLK; i += 256) s += blk_obj[i];  // obj-BCE base (plain stores from kGXA)
#pragma unroll
    for (int off = 32; off; off >>= 1) s += __shfl_down(s, off, 64);
    if ((tid & 63) == 0) s_red[tid >> 6] = s;
    __syncthreads();
    if (tid == 0) {
      float obj_base = s_red[0] + s_red[1] + s_red[2] + s_red[3];
      // coherent read-backs of device-scope accumulators
      float loss_iou = atomicAdd(&accum[0], 0.0f);
      float oex      = atomicAdd(&accum[2], 0.0f);
      float loss_cls = atomicAdd(&accum[3], 0.0f);
      float num_fg   = atomicAdd(&accum[4], 0.0f);
      float loss_obj = obj_base - oex;
      out[0] = (5.0f * loss_iou + loss_obj + loss_cls) / fmaxf(num_fg, 1.0f);
    }
  }
}

// ---------- launch ----------
extern "C" void kernel_launch(void* const* d_in, const int* in_sizes, int n_in,
                              void* d_out, int out_size, void* d_ws, size_t ws_size,
                              hipStream_t stream) {
  const float* p8     = (const float*)d_in[0];
  const float* p16    = (const float*)d_in[1];
  const float* p32    = (const float*)d_in[2];
  const float* labels = (const float*)d_in[3];
  float* out = (float*)d_out;

  const size_t BAP = (size_t)NB * NAP;     // 270336
  char* w = (char*)d_ws;
  float4*       bbox_c  = (float4*)w;                              // 16B-aligned, 4.3 MB
  float*        w_c     = (float*)(w + BAP * 16);                  // NB*NG*NAP*4 = 21.6 MB
  char*         w2      = w + BAP * 16 + (size_t)NB * NG * NAP * 4;
  int*          fg_list = (int*)(w2);
  unsigned int* am_c    = (unsigned int*)(w2 + BAP * 4);
  unsigned int* match_c = (unsigned int*)(w2 + BAP * 8);
  float*        sl_c    = (float*)(w2 + BAP * 12);
  float*        sb_c    = (float*)(w2 + BAP * 16);
  char*         w3      = w2 + BAP * 20;
  // zeroed region: n_fg_cnt (NB ints) + accum (8 f) + done_cnt (1 int), contiguous 256 B
  int*          n_fg    = (int*)w3;
  float*        accum   = (float*)(w3 + 128);
  int*          done_cnt= (int*)(w3 + 160);
  float*        blk_obj = (float*)(w3 + 256);                      // NB*NBLK floats, no zero needed

  hipMemsetAsync(w3, 0, 256, stream);

  kGXA<<<dim3(NBLK, NB), dim3(256), 0, stream>>>(p8, p16, p32, labels, n_fg, fg_list, am_c,
                                                 bbox_c, sl_c, sb_c, w_c, match_c, blk_obj);
  kB<<<dim3(NG, NB), dim3(256), 0, stream>>>(labels, bbox_c, sl_c, w_c, am_c, n_fg, match_c);
  kCD<<<dim3(KC_BLKS, NB), dim3(256), 0, stream>>>(p8, p16, p32, labels, bbox_c, sl_c, sb_c,
                                                   w_c, am_c, fg_list, n_fg, match_c, blk_obj,
                                                   accum, done_cnt, out);
}

// Round 7
// 181.158 us; speedup vs baseline: 2.5653x; 1.0028x over previous
//
#include <hip/hip_runtime.h>
#include <cstdint>
#include <cstddef>

#define NA 8400   // anchors per image: 80*80 + 40*40 + 20*20
#define NAP 8448  // padded stride (33*256)
#define NB 32     // batch
#define NG 20     // ground truths per image
#define NCL 80    // classes
#define NBLK 33   // 256-thread blocks per image
#define KC_BLKS 12

// ---------- fast math ----------
__device__ __forceinline__ float frcp(float x) { return __builtin_amdgcn_rcpf(x); }
__device__ __forceinline__ float bce0(float x) {
  return fmaxf(x, 0.0f) + __logf(1.0f + __expf(-fabsf(x)));
}

__device__ __forceinline__ void anchor_info(int a, const float* p8, const float* p16,
                                            const float* p32, int b, const float*& base,
                                            int& hw, int& HW, int& xg, int& yg, float& fs) {
  if (a < 6400)      { hw = a;        HW = 6400; xg = hw % 80; yg = hw / 80; fs = 8.f;
                       base = p8  + (size_t)b * 85 * 6400; }
  else if (a < 8000) { hw = a - 6400; HW = 1600; xg = hw % 40; yg = hw / 40; fs = 16.f;
                       base = p16 + (size_t)b * 85 * 1600; }
  else               { hw = a - 8000; HW = 400;  xg = hw % 20; yg = hw / 20; fs = 32.f;
                       base = p32 + (size_t)b * 85 * 400; }
}

__device__ __forceinline__ float iou_raw(float gx, float gy, float gw, float gh, float4 p) {
  float gtlx = gx - gw * 0.5f, gtly = gy - gh * 0.5f;
  float gbrx = gx + gw * 0.5f, gbry = gy + gh * 0.5f;
  float ptlx = p.x - p.z * 0.5f, ptly = p.y - p.w * 0.5f;
  float pbrx = p.x + p.z * 0.5f, pbry = p.y + p.w * 0.5f;
  float tlx = fmaxf(gtlx, ptlx), tly = fmaxf(gtly, ptly);
  float brx = fminf(gbrx, pbrx), bry = fminf(gbry, pbry);
  float inter = ((tlx < brx) && (tly < bry)) ? (brx - tlx) * (bry - tly) : 0.0f;
  float ag = gw * gh, ap = p.z * p.w;
  return inter * frcp(ag + ap - inter + 1e-16f);
}

__device__ __forceinline__ float giou_loss(float4 bb, float gx, float gy, float gw, float gh) {
  float btlx = bb.x - bb.z * 0.5f, btly = bb.y - bb.w * 0.5f;
  float bbrx = bb.x + bb.z * 0.5f, bbry = bb.y + bb.w * 0.5f;
  float gtlx = gx - gw * 0.5f, gtly = gy - gh * 0.5f;
  float gbrx = gx + gw * 0.5f, gbry = gy + gh * 0.5f;
  float tlx = fmaxf(btlx, gtlx), tly = fmaxf(btly, gtly);
  float brx = fminf(bbrx, gbrx), bry = fminf(bbry, gbry);
  float area_b = bb.z * bb.w, area_g = gw * gh;
  float inter = ((tlx < brx) && (tly < bry)) ? (brx - tlx) * (bry - tly) : 0.0f;
  float uni = area_b + area_g - inter;
  float iou = inter / (uni + 1e-16f);
  float ctlx = fminf(btlx, gtlx), ctly = fminf(btly, gtly);
  float cbrx = fmaxf(bbrx, gbrx), cbry = fmaxf(bbry, gbry);
  float area_c = fmaxf((cbrx - ctlx) * (cbry - ctly), 1e-16f);
  float giou = iou - (area_c - uni) / area_c;
  giou = fminf(fmaxf(giou, -1.0f), 1.0f);
  return 1.0f - giou;
}

__device__ __forceinline__ void block_argmin(float& v, int& i, volatile float* s_v,
                                             volatile int* s_i, int tid) {
#pragma unroll
  for (int off = 32; off; off >>= 1) {
    float ov = __shfl_down(v, off, 64);
    int   oi = __shfl_down(i, off, 64);
    if (ov < v || (ov == v && oi < i)) { v = ov; i = oi; }
  }
  if ((tid & 63) == 0) { s_v[tid >> 6] = v; s_i[tid >> 6] = i; }
  __syncthreads();
  v = s_v[0]; i = s_i[0];
#pragma unroll
  for (int w = 1; w < 4; ++w) {
    float ov = s_v[w]; int oi = s_i[w];
    if (ov < v || (ov == v && oi < i)) { v = ov; i = oi; }
  }
}

// ---------- kGXA: geometry + compaction + DENSE heavy pass + cost/iou tables ----------
__global__ __launch_bounds__(256) void kGXA(const float* __restrict__ p8,
                                            const float* __restrict__ p16,
                                            const float* __restrict__ p32,
                                            const float* __restrict__ labels,
                                            int* __restrict__ n_fg_cnt,
                                            int* __restrict__ fg_list,
                                            float4* __restrict__ bbox_c,
                                            float* __restrict__ sb_c,
                                            float* __restrict__ cost_tbl,
                                            float* __restrict__ iou_tbl,
                                            unsigned int* __restrict__ match_c,
                                            float* __restrict__ blk_obj) {
  __shared__ float s_gt[NG * 4];
  __shared__ int   s_gcls[NG];
  __shared__ int   s_a[256];
  __shared__ unsigned int s_msk[256];
  __shared__ float s_lso[256];
  __shared__ unsigned int s_wcnt[4];
  __shared__ float s_part[4];
  __shared__ unsigned int s_base;
  __shared__ int s_c;
  int blk = blockIdx.x, b = blockIdx.y, tid = threadIdx.x, lane = tid & 63, wid = tid >> 6;

  if (tid < NG) {
    s_gt[tid * 4 + 0] = labels[((size_t)b * NG + tid) * 5 + 0];
    s_gt[tid * 4 + 1] = labels[((size_t)b * NG + tid) * 5 + 1];
    s_gt[tid * 4 + 2] = labels[((size_t)b * NG + tid) * 5 + 2];
    s_gt[tid * 4 + 3] = labels[((size_t)b * NG + tid) * 5 + 3];
    s_gcls[tid] = (int)labels[((size_t)b * NG + tid) * 5 + 4];
  }
  __syncthreads();

  int a = blk * 256 + tid;
  match_c[(size_t)b * NAP + a] = 0u;     // NBLK*256 == NAP: full coverage

  bool fg = false;
  unsigned int msk = 0u;
  float bce_obj = 0.0f, obj = 0.0f;
  if (a < NA) {
    const float* base; int hw, HW, xg, yg; float fs;
    anchor_info(a, p8, p16, p32, b, base, hw, HW, xg, yg, fs);
    obj = base[4 * HW + hw];             // coalesced obj-plane stream
    bce_obj = bce0(obj);
    float xc = ((float)xg + 0.5f) * fs;
    float yc = ((float)yg + 0.5f) * fs;
    float r = 2.5f * fs;
#pragma unroll
    for (int g = 0; g < NG; ++g) {
      float gx = s_gt[g * 4 + 0], gy = s_gt[g * 4 + 1];
      float gw = s_gt[g * 4 + 2], gh = s_gt[g * 4 + 3];
      bool inb = (xc > gx - 0.5f * gw) && (xc < gx + 0.5f * gw) &&
                 (yc > gy - 0.5f * gh) && (yc < gy + 0.5f * gh);
      bool inc = (xc > gx - r) && (xc < gx + r) && (yc > gy - r) && (yc < gy + r);
      fg = fg || inb || inc;
      if (inb && inc) msk |= (1u << g);
    }
  }

  unsigned long long bm = __ballot(fg);
#pragma unroll
  for (int off = 32; off; off >>= 1) bce_obj += __shfl_down(bce_obj, off, 64);
  if (lane == 0) { s_wcnt[wid] = (unsigned int)__popcll(bm); s_part[wid] = bce_obj; }
  __syncthreads();
  if (tid == 0) {
    unsigned int cnt = s_wcnt[0] + s_wcnt[1] + s_wcnt[2] + s_wcnt[3];
    s_c = (int)cnt;
    s_base = cnt ? (unsigned int)atomicAdd(&n_fg_cnt[b], (int)cnt) : 0u;
    blk_obj[b * NBLK + blk] = s_part[0] + s_part[1] + s_part[2] + s_part[3];
  }
  // write block-local compacted list (fg threads only, divergent but cheap)
  if (fg) {
    unsigned int li = 0;
    for (int w = 0; w < wid; ++w) li += s_wcnt[w];
    li += (unsigned int)__popcll(bm & ((1ull << lane) - 1ull));
    s_a[li] = a;
    s_msk[li] = msk;
    // log(sigmoid(obj)) = min(obj,0) - log(1+exp(-|obj|))
    float uo = __logf(1.0f + __expf(-fabsf(obj)));
    s_lso[li] = fminf(obj, 0.0f) - uo;
  }
  __syncthreads();

  // DENSE phase: threads 0..c-1 each own one compacted anchor (full lane density,
  // coalesced loads: consecutive rank -> consecutive anchor index)
  int c = s_c;
  if (tid >= c) return;
  int ci = (int)s_base + tid;
  size_t bo = (size_t)b * NAP;
  int aa = s_a[tid];
  unsigned int mk = s_msk[tid];
  float lso = s_lso[tid];

  const float* base; int hw, HW, xg, yg; float fs;
  anchor_info(aa, p8, p16, p32, b, base, hw, HW, xg, yg, fs);
  fg_list[bo + ci] = aa;

  float v0 = base[hw];
  float v1 = base[HW + hw];
  float v2 = base[2 * HW + hw];
  float v3 = base[3 * HW + hw];
  float4 pb = make_float4((v0 + (float)xg) * fs, (v1 + (float)yg) * fs,
                          __expf(v2) * fs, __expf(v3) * fs);
  bbox_c[bo + ci] = pb;

  // pass 1: accumulate sl (sum of l1p over all classes) and sb (sum of bce0)
  float sl = 0.0f, sb = 0.0f;
  for (int cc = 0; cc < NCL; cc += 8) {
    float xs[8];
#pragma unroll
    for (int j = 0; j < 8; ++j) xs[j] = base[(5 + cc + j) * HW + hw];
#pragma unroll
    for (int j = 0; j < 8; ++j) {
      float x = xs[j];
      float u = __logf(1.0f + __expf(-fabsf(x)));
      sb += fmaxf(x, 0.0f) + u;                 // bce(x,0)
      float lsx = fminf(x, 0.0f) - u;           // log(sigmoid(x))
      float lpr = 0.5f * (lsx + lso);           // log p
      float p   = __expf(lpr);
      sl += fmaxf(__logf(1.0f - p), -100.0f);
    }
  }
  sb_c[bo + ci] = sb;

  // pass 2: per-GT cost and iou (GT-class logits reload is L1-hot; arithmetic
  // bit-identical to pass 1 so w is consistent with sl's terms)
  for (int g = 0; g < NG; ++g) {
    int cg = s_gcls[g];
    float x = base[(5 + cg) * HW + hw];
    float u = __logf(1.0f + __expf(-fabsf(x)));
    float lsx = fminf(x, 0.0f) - u;
    float lpr = 0.5f * (lsx + lso);
    float p   = __expf(lpr);
    float l1p = fmaxf(__logf(1.0f - p), -100.0f);
    float wv  = fmaxf(lpr, -100.0f) - l1p;      // lp - l1p
    float iou = iou_raw(s_gt[g * 4 + 0], s_gt[g * 4 + 1], s_gt[g * 4 + 2], s_gt[g * 4 + 3], pb);
    float cst = -(wv + sl) - 3.0f * __logf(iou + 1e-8f);
    if (!((mk >> g) & 1u)) cst += 100000.0f;
    size_t row = ((size_t)b * NG + g) * NAP + ci;
    cost_tbl[row] = cst;
    iou_tbl[row]  = iou;
  }
}

// ---------- kB: per (b,g) streaming row + dyn_k top-k selection ----------
__global__ __launch_bounds__(256) void kB(const float* __restrict__ cost_tbl,
                                          const float* __restrict__ iou_tbl,
                                          const int* __restrict__ n_fg,
                                          unsigned int* __restrict__ match_c) {
  __shared__ float s_cost[NAP];   // 33 KB (only n used)
  __shared__ float s_wt[4 * 10];
  __shared__ float s_v[4];
  __shared__ int   s_i[4];
  __shared__ int   s_k;

  int g = blockIdx.x, b = blockIdx.y, tid = threadIdx.x;
  int lane = tid & 63, wid = tid >> 6;
  int n = n_fg[b];
  size_t bo = (size_t)b * NAP;
  const float* __restrict__ cg = cost_tbl + ((size_t)b * NG + g) * NAP;
  const float* __restrict__ ig = iou_tbl  + ((size_t)b * NG + g) * NAP;

  float t10[10];
#pragma unroll
  for (int j = 0; j < 10; ++j) t10[j] = 0.0f;

  // streaming fill: 2 loads/ci, no transcendentals
  for (int ci = tid; ci < n; ci += 256) {
    float iou = ig[ci];
    float cst = cg[ci];
    if (iou > t10[9]) {
      t10[9] = iou;
#pragma unroll
      for (int q = 9; q > 0; --q) {
        if (t10[q] > t10[q - 1]) { float t = t10[q]; t10[q] = t10[q - 1]; t10[q - 1] = t; }
        else break;
      }
    }
    s_cost[ci] = cst;
  }

  // per-wave top-10 extraction (regs+shuffles, no syncs), then 4-list merge
  for (int r = 0; r < 10; ++r) {
    float v = t10[0];
    float bv = v;
#pragma unroll
    for (int off = 32; off; off >>= 1) bv = fmaxf(bv, __shfl_down(bv, off, 64));
    bv = __shfl(bv, 0, 64);
    unsigned long long won = __ballot(v == bv);
    if (lane == __ffsll(won) - 1) {
#pragma unroll
      for (int q = 0; q < 9; ++q) t10[q] = t10[q + 1];
      t10[9] = -1.0f;
    }
    if (lane == 0) s_wt[wid * 10 + r] = bv;
  }
  __syncthreads();

  if (tid == 0) {
    int p0 = 0, p1 = 0, p2 = 0, p3 = 0;
    float s = 0.0f;
    for (int r = 0; r < 10; ++r) {
      float v0 = (p0 < 10) ? s_wt[p0]      : -2.0f;
      float v1 = (p1 < 10) ? s_wt[10 + p1] : -2.0f;
      float v2 = (p2 < 10) ? s_wt[20 + p2] : -2.0f;
      float v3 = (p3 < 10) ? s_wt[30 + p3] : -2.0f;
      float m = fmaxf(fmaxf(v0, v1), fmaxf(v2, v3));
      s += m;
      if (m == v0) ++p0; else if (m == v1) ++p1; else if (m == v2) ++p2; else ++p3;
    }
    int k = (int)s;                 // truncation matches astype(int32)
    if (k < 1) k = 1;
    s_k = k;
  }
  __syncthreads();
  int k = s_k;

  // extract k smallest among candidates (all compacted entries are fg_cand)
  for (int it = 0; it < k; ++it) {
    float bv = 3.4e38f; int bi = NAP;
    for (int ci = tid; ci < n; ci += 256) {
      float v = s_cost[ci];
      if (v < bv || (v == bv && ci < bi)) { bv = v; bi = ci; }
    }
    block_argmin(bv, bi, s_v, s_i, tid);
    if (bv >= 1e8f) break;          // unreachable safety (costs <= ~1.1e5)
    if (tid == 0) {
      atomicOr(&match_c[bo + bi], 1u << g);
      s_cost[bi] = 3.4e38f;
    }
    __syncthreads();
  }
}

// ---------- kCD: finalize matched anchors + last-block scalar epilogue ----------
__global__ __launch_bounds__(256) void kCD(const float* __restrict__ p8,
                                           const float* __restrict__ p16,
                                           const float* __restrict__ p32,
                                           const float* __restrict__ labels,
                                           const float4* __restrict__ bbox_c,
                                           const float* __restrict__ sb_c,
                                           const float* __restrict__ cost_tbl,
                                           const float* __restrict__ iou_tbl,
                                           const int* __restrict__ fg_list,
                                           const int* __restrict__ n_fg,
                                           const unsigned int* __restrict__ match_c,
                                           const float* __restrict__ blk_obj,
                                           float* __restrict__ accum,
                                           int* __restrict__ done_cnt,
                                           float* __restrict__ out) {
  __shared__ float s_gt[NG * 5];
  __shared__ float s_red[16];
  __shared__ int s_last;
  int b = blockIdx.y, tid = threadIdx.x;
  if (tid < NG * 5) s_gt[tid] = labels[(size_t)b * NG * 5 + tid];
  __syncthreads();

  int n = n_fg[b];
  size_t bo = (size_t)b * NAP;
  float li = 0.0f, oe = 0.0f, lc = 0.0f, nf = 0.0f;

  for (int ci = blockIdx.x * 256 + tid; ci < n; ci += KC_BLKS * 256) {
    unsigned int m = match_c[bo + ci];
    if (m == 0u) continue;
    int mg;
    if (m & (m - 1)) {
      // multi-matched: argmin over ALL g of precomputed cost (first-min tie-break)
      float bestc = 3.4e38f; mg = 0;
#pragma unroll 4
      for (int g = 0; g < NG; ++g) {
        float cst = cost_tbl[((size_t)b * NG + g) * NAP + ci];
        if (cst < bestc) { bestc = cst; mg = g; }
      }
    } else {
      mg = __ffs(m) - 1;
    }
    int a = fg_list[bo + ci];
    const float* base; int hw, HW, xg, yg; float fs;
    anchor_info(a, p8, p16, p32, b, base, hw, HW, xg, yg, fs);
    float4 pb = bbox_c[bo + ci];
    float gx = s_gt[mg * 5], gy = s_gt[mg * 5 + 1];
    float gw = s_gt[mg * 5 + 2], gh = s_gt[mg * 5 + 3];
    int cg = (int)s_gt[mg * 5 + 4];
    float piou = iou_tbl[((size_t)b * NG + mg) * NAP + ci];
    li += giou_loss(pb, gx, gy, gw, gh);
    float xcls = base[(5 + cg) * HW + hw];
    lc += sb_c[bo + ci] - xcls * piou;   // bce(x,t) = bce(x,0) - x*t
    oe += base[4 * HW + hw];             // obj logit: bce(x,1) = bce(x,0) - x
    nf += 1.0f;
  }

  float vals[4] = {li, oe, lc, nf};
#pragma unroll
  for (int q = 0; q < 4; ++q) {
#pragma unroll
    for (int off = 32; off; off >>= 1) vals[q] += __shfl_down(vals[q], off, 64);
  }
  if ((tid & 63) == 0) {
    int wid = tid >> 6;
    s_red[wid * 4 + 0] = vals[0];
    s_red[wid * 4 + 1] = vals[1];
    s_red[wid * 4 + 2] = vals[2];
    s_red[wid * 4 + 3] = vals[3];
  }
  __syncthreads();
  if (tid < 4) {
    const int slot[4] = {0, 2, 3, 4};
    float s = s_red[tid] + s_red[4 + tid] + s_red[8 + tid] + s_red[12 + tid];
    atomicAdd(&accum[slot[tid]], s);
  }

  // done-ticket: last block computes the scalar output
  if (tid == 0) {
    __threadfence();
    int old = atomicAdd(done_cnt, 1);
    s_last = (old == KC_BLKS * NB - 1) ? 1 : 0;
  }
  __syncthreads();
  if (s_last) {
    float s = 0.0f;
    for (int i = tid; i < NB * NBLK; i += 256) s += blk_obj[i];  // obj-BCE base
#pragma unroll
    for (int off = 32; off; off >>= 1) s += __shfl_down(s, off, 64);
    if ((tid & 63) == 0) s_red[tid >> 6] = s;
    __syncthreads();
    if (tid == 0) {
      float obj_base = s_red[0] + s_red[1] + s_red[2] + s_red[3];
      float loss_iou = atomicAdd(&accum[0], 0.0f);   // coherent read-backs
      float oex      = atomicAdd(&accum[2], 0.0f);
      float loss_cls = atomicAdd(&accum[3], 0.0f);
      float num_fg   = atomicAdd(&accum[4], 0.0f);
      float loss_obj = obj_base - oex;
      out[0] = (5.0f * loss_iou + loss_obj + loss_cls) / fmaxf(num_fg, 1.0f);
    }
  }
}

// ---------- launch ----------
extern "C" void kernel_launch(void* const* d_in, const int* in_sizes, int n_in,
                              void* d_out, int out_size, void* d_ws, size_t ws_size,
                              hipStream_t stream) {
  const float* p8     = (const float*)d_in[0];
  const float* p16    = (const float*)d_in[1];
  const float* p32    = (const float*)d_in[2];
  const float* labels = (const float*)d_in[3];
  float* out = (float*)d_out;

  const size_t BAP = (size_t)NB * NAP;     // 270336
  char* w = (char*)d_ws;
  float4*       bbox_c   = (float4*)w;                             // 4.3 MB, 16B-aligned
  float*        cost_tbl = (float*)(w + BAP * 16);                 // NB*NG*NAP*4 = 21.6 MB
  float*        iou_tbl  = cost_tbl + (size_t)NB * NG * NAP;       // 21.6 MB
  char*         w2       = (char*)(iou_tbl + (size_t)NB * NG * NAP);
  int*          fg_list  = (int*)(w2);
  unsigned int* match_c  = (unsigned int*)(w2 + BAP * 4);
  float*        sb_c     = (float*)(w2 + BAP * 8);
  char*         w3       = w2 + BAP * 12;
  // zeroed region: n_fg_cnt (NB ints) + accum (8 f) + done_cnt (1 int) = 256 B
  int*          n_fg     = (int*)w3;
  float*        accum    = (float*)(w3 + 128);
  int*          done_cnt = (int*)(w3 + 160);
  float*        blk_obj  = (float*)(w3 + 256);                     // NB*NBLK floats

  hipMemsetAsync(w3, 0, 256, stream);

  kGXA<<<dim3(NBLK, NB), dim3(256), 0, stream>>>(p8, p16, p32, labels, n_fg, fg_list,
                                                 bbox_c, sb_c, cost_tbl, iou_tbl,
                                                 match_c, blk_obj);
  kB<<<dim3(NG, NB), dim3(256), 0, stream>>>(cost_tbl, iou_tbl, n_fg, match_c);
  kCD<<<dim3(KC_BLKS, NB), dim3(256), 0, stream>>>(p8, p16, p32, labels, bbox_c, sb_c,
                                                   cost_tbl, iou_tbl, fg_list, n_fg,
                                                   match_c, blk_obj, accum, done_cnt, out);
}

// Round 8
// 173.385 us; speedup vs baseline: 2.6803x; 1.0448x over previous
//
#include <hip/hip_runtime.h>
#include <cstdint>
#include <cstddef>

#define NA 8400   // anchors per image: 80*80 + 40*40 + 20*20
#define NAP 8448  // padded stride (33*256)
#define NB 32     // batch
#define NG 20     // ground truths per image
#define NCL 80    // classes
#define NBLK 33   // 256-thread blocks per image
#define KC_BLKS 12

// ---------- fast math ----------
__device__ __forceinline__ float frcp(float x) { return __builtin_amdgcn_rcpf(x); }
__device__ __forceinline__ float bce0(float x) {
  return fmaxf(x, 0.0f) + __logf(1.0f + __expf(-fabsf(x)));
}

__device__ __forceinline__ void anchor_info(int a, const float* p8, const float* p16,
                                            const float* p32, int b, const float*& base,
                                            int& hw, int& HW, int& xg, int& yg, float& fs) {
  if (a < 6400)      { hw = a;        HW = 6400; xg = hw % 80; yg = hw / 80; fs = 8.f;
                       base = p8  + (size_t)b * 85 * 6400; }
  else if (a < 8000) { hw = a - 6400; HW = 1600; xg = hw % 40; yg = hw / 40; fs = 16.f;
                       base = p16 + (size_t)b * 85 * 1600; }
  else               { hw = a - 8000; HW = 400;  xg = hw % 20; yg = hw / 20; fs = 32.f;
                       base = p32 + (size_t)b * 85 * 400; }
}

__device__ __forceinline__ float iou_raw(float gx, float gy, float gw, float gh, float4 p) {
  float gtlx = gx - gw * 0.5f, gtly = gy - gh * 0.5f;
  float gbrx = gx + gw * 0.5f, gbry = gy + gh * 0.5f;
  float ptlx = p.x - p.z * 0.5f, ptly = p.y - p.w * 0.5f;
  float pbrx = p.x + p.z * 0.5f, pbry = p.y + p.w * 0.5f;
  float tlx = fmaxf(gtlx, ptlx), tly = fmaxf(gtly, ptly);
  float brx = fminf(gbrx, pbrx), bry = fminf(gbry, pbry);
  float inter = ((tlx < brx) && (tly < bry)) ? (brx - tlx) * (bry - tly) : 0.0f;
  float ag = gw * gh, ap = p.z * p.w;
  return inter * frcp(ag + ap - inter + 1e-16f);
}

__device__ __forceinline__ float giou_loss(float4 bb, float gx, float gy, float gw, float gh) {
  float btlx = bb.x - bb.z * 0.5f, btly = bb.y - bb.w * 0.5f;
  float bbrx = bb.x + bb.z * 0.5f, bbry = bb.y + bb.w * 0.5f;
  float gtlx = gx - gw * 0.5f, gtly = gy - gh * 0.5f;
  float gbrx = gx + gw * 0.5f, gbry = gy + gh * 0.5f;
  float tlx = fmaxf(btlx, gtlx), tly = fmaxf(btly, gtly);
  float brx = fminf(bbrx, gbrx), bry = fminf(bbry, gbry);
  float area_b = bb.z * bb.w, area_g = gw * gh;
  float inter = ((tlx < brx) && (tly < bry)) ? (brx - tlx) * (bry - tly) : 0.0f;
  float uni = area_b + area_g - inter;
  float iou = inter / (uni + 1e-16f);
  float ctlx = fminf(btlx, gtlx), ctly = fminf(btly, gtly);
  float cbrx = fmaxf(bbrx, gbrx), cbry = fmaxf(bbry, gbry);
  float area_c = fmaxf((cbrx - ctlx) * (cbry - ctly), 1e-16f);
  float giou = iou - (area_c - uni) / area_c;
  giou = fminf(fmaxf(giou, -1.0f), 1.0f);
  return 1.0f - giou;
}

__device__ __forceinline__ void block_argmin(float& v, int& i, volatile float* s_v,
                                             volatile int* s_i, int tid) {
#pragma unroll
  for (int off = 32; off; off >>= 1) {
    float ov = __shfl_down(v, off, 64);
    int   oi = __shfl_down(i, off, 64);
    if (ov < v || (ov == v && oi < i)) { v = ov; i = oi; }
  }
  if ((tid & 63) == 0) { s_v[tid >> 6] = v; s_i[tid >> 6] = i; }
  __syncthreads();
  v = s_v[0]; i = s_i[0];
#pragma unroll
  for (int w = 1; w < 4; ++w) {
    float ov = s_v[w]; int oi = s_i[w];
    if (ov < v || (ov == v && oi < i)) { v = ov; i = oi; }
  }
}

// ---------- k1: geometry + compaction + bbox/lso decode + obj-BCE ----------
__global__ __launch_bounds__(256) void k1(const float* __restrict__ p8,
                                          const float* __restrict__ p16,
                                          const float* __restrict__ p32,
                                          const float* __restrict__ labels,
                                          int* __restrict__ n_fg_cnt,
                                          int* __restrict__ fg_list,
                                          unsigned int* __restrict__ am_c,
                                          float4* __restrict__ bbox_c,
                                          float* __restrict__ lso_c,
                                          unsigned int* __restrict__ match_c,
                                          float* __restrict__ blk_obj) {
  __shared__ float s_gt[NG * 4];
  __shared__ unsigned int s_wcnt[4];
  __shared__ float s_part[4];
  __shared__ unsigned int s_base;
  int blk = blockIdx.x, b = blockIdx.y, tid = threadIdx.x, lane = tid & 63, wid = tid >> 6;

  if (tid < NG) {
    s_gt[tid * 4 + 0] = labels[((size_t)b * NG + tid) * 5 + 0];
    s_gt[tid * 4 + 1] = labels[((size_t)b * NG + tid) * 5 + 1];
    s_gt[tid * 4 + 2] = labels[((size_t)b * NG + tid) * 5 + 2];
    s_gt[tid * 4 + 3] = labels[((size_t)b * NG + tid) * 5 + 3];
  }
  __syncthreads();

  int a = blk * 256 + tid;
  match_c[(size_t)b * NAP + a] = 0u;     // NBLK*256 == NAP: full coverage

  bool fg = false;
  unsigned int msk = 0u;
  float bce_obj = 0.0f, obj = 0.0f;
  const float* base = nullptr; int hw = 0, HW = 0, xg = 0, yg = 0; float fs = 8.f;
  if (a < NA) {
    anchor_info(a, p8, p16, p32, b, base, hw, HW, xg, yg, fs);
    obj = base[4 * HW + hw];             // coalesced obj-plane stream
    bce_obj = bce0(obj);
    float xc = ((float)xg + 0.5f) * fs;
    float yc = ((float)yg + 0.5f) * fs;
    float r = 2.5f * fs;
#pragma unroll
    for (int g = 0; g < NG; ++g) {
      float gx = s_gt[g * 4 + 0], gy = s_gt[g * 4 + 1];
      float gw = s_gt[g * 4 + 2], gh = s_gt[g * 4 + 3];
      bool inb = (xc > gx - 0.5f * gw) && (xc < gx + 0.5f * gw) &&
                 (yc > gy - 0.5f * gh) && (yc < gy + 0.5f * gh);
      bool inc = (xc > gx - r) && (xc < gx + r) && (yc > gy - r) && (yc < gy + r);
      fg = fg || inb || inc;
      if (inb && inc) msk |= (1u << g);
    }
  }

  unsigned long long bm = __ballot(fg);
#pragma unroll
  for (int off = 32; off; off >>= 1) bce_obj += __shfl_down(bce_obj, off, 64);
  if (lane == 0) { s_wcnt[wid] = (unsigned int)__popcll(bm); s_part[wid] = bce_obj; }
  __syncthreads();
  if (tid == 0) {
    unsigned int cnt = s_wcnt[0] + s_wcnt[1] + s_wcnt[2] + s_wcnt[3];
    s_base = cnt ? (unsigned int)atomicAdd(&n_fg_cnt[b], (int)cnt) : 0u;
    blk_obj[b * NBLK + blk] = s_part[0] + s_part[1] + s_part[2] + s_part[3];
  }
  __syncthreads();

  if (!fg) return;
  unsigned int pos = s_base;
  for (int w = 0; w < wid; ++w) pos += s_wcnt[w];
  pos += (unsigned int)__popcll(bm & ((1ull << lane) - 1ull));
  size_t bo = (size_t)b * NAP;
  int ci = (int)pos;
  fg_list[bo + ci] = a;
  am_c[bo + ci] = msk;

  float v0 = base[hw];
  float v1 = base[HW + hw];
  float v2 = base[2 * HW + hw];
  float v3 = base[3 * HW + hw];
  bbox_c[bo + ci] = make_float4((v0 + (float)xg) * fs, (v1 + (float)yg) * fs,
                                __expf(v2) * fs, __expf(v3) * fs);
  // log(sigmoid(obj)) = min(obj,0) - log(1+exp(-|obj|))
  float uo = __logf(1.0f + __expf(-fabsf(obj)));
  lso_c[bo + ci] = fminf(obj, 0.0f) - uo;
}

// ---------- k2: class sums, 8 threads per anchor (10 classes each) ----------
// tid = part*32 + ci_local : a wave covers 2 parts x 32 consecutive anchors,
// so each plane-load is 32-consecutive-ish (coalesced); 8x the waves of the
// 1-thread/anchor version and 8x shorter dependent chains.
__global__ __launch_bounds__(256) void k2(const float* __restrict__ p8,
                                          const float* __restrict__ p16,
                                          const float* __restrict__ p32,
                                          const int* __restrict__ fg_list,
                                          const int* __restrict__ n_fg,
                                          const float* __restrict__ lso_c,
                                          float* __restrict__ sl_c,
                                          float* __restrict__ sb_c) {
  __shared__ float s_sl[8][33];
  __shared__ float s_sb[8][33];
  int b = blockIdx.y, tid = threadIdx.x;
  int part = tid >> 5, cl = tid & 31;
  int n = n_fg[b];
  size_t bo = (size_t)b * NAP;

  for (int base_ci = blockIdx.x * 32; base_ci < n; base_ci += gridDim.x * 32) {
    int ci = base_ci + cl;
    bool act = ci < n;
    float sl = 0.0f, sb = 0.0f;
    if (act) {
      int a = fg_list[bo + ci];
      float lso = lso_c[bo + ci];
      const float* base; int hw, HW, xg, yg; float fs;
      anchor_info(a, p8, p16, p32, b, base, hw, HW, xg, yg, fs);
      const float* cb = base + (size_t)(5 + part * 10) * HW + hw;
      float xs[10];
#pragma unroll
      for (int j = 0; j < 5; ++j) xs[j] = cb[j * HW];
#pragma unroll
      for (int j = 5; j < 10; ++j) xs[j] = cb[j * HW];
#pragma unroll
      for (int j = 0; j < 10; ++j) {
        float x = xs[j];
        float u = __logf(1.0f + __expf(-fabsf(x)));
        sb += fmaxf(x, 0.0f) + u;                 // bce(x,0)
        float lsx = fminf(x, 0.0f) - u;           // log(sigmoid(x))
        float lpr = 0.5f * (lsx + lso);           // log p
        float p   = __expf(lpr);
        sl += fmaxf(__logf(1.0f - p), -100.0f);
      }
    }
    s_sl[part][cl] = sl;
    s_sb[part][cl] = sb;
    __syncthreads();
    if (tid < 32 && base_ci + tid < n) {
      float tsl = 0.0f, tsb = 0.0f;
#pragma unroll
      for (int q = 0; q < 8; ++q) { tsl += s_sl[q][tid]; tsb += s_sb[q][tid]; }
      sl_c[bo + base_ci + tid] = tsl;
      sb_c[bo + base_ci + tid] = tsb;
    }
    __syncthreads();
  }
}

// ---------- k3: cost/iou tables, 1 thread per (g, ci) ----------
__global__ __launch_bounds__(256) void k3(const float* __restrict__ p8,
                                          const float* __restrict__ p16,
                                          const float* __restrict__ p32,
                                          const float* __restrict__ labels,
                                          const int* __restrict__ fg_list,
                                          const int* __restrict__ n_fg,
                                          const float* __restrict__ lso_c,
                                          const float* __restrict__ sl_c,
                                          const float4* __restrict__ bbox_c,
                                          const unsigned int* __restrict__ am_c,
                                          float* __restrict__ cost_tbl,
                                          float* __restrict__ iou_tbl) {
  int g = blockIdx.y, b = blockIdx.z, tid = threadIdx.x;
  int n = n_fg[b];
  size_t bo = (size_t)b * NAP;
  float gx = labels[((size_t)b * NG + g) * 5 + 0];
  float gy = labels[((size_t)b * NG + g) * 5 + 1];
  float gw = labels[((size_t)b * NG + g) * 5 + 2];
  float gh = labels[((size_t)b * NG + g) * 5 + 3];
  int   cg = (int)labels[((size_t)b * NG + g) * 5 + 4];
  size_t row = ((size_t)b * NG + g) * NAP;

  for (int ci = blockIdx.x * 256 + tid; ci < n; ci += gridDim.x * 256) {
    int a = fg_list[bo + ci];
    unsigned int am = am_c[bo + ci];
    float lso = lso_c[bo + ci];
    float sl  = sl_c[bo + ci];
    float4 pb = bbox_c[bo + ci];
    const float* base; int hw, HW, xg, yg; float fs;
    anchor_info(a, p8, p16, p32, b, base, hw, HW, xg, yg, fs);
    float x = base[(size_t)(5 + cg) * HW + hw];

    float u = __logf(1.0f + __expf(-fabsf(x)));
    float lsx = fminf(x, 0.0f) - u;
    float lpr = 0.5f * (lsx + lso);
    float p   = __expf(lpr);
    float l1p = fmaxf(__logf(1.0f - p), -100.0f);
    float wv  = fmaxf(lpr, -100.0f) - l1p;        // lp - l1p
    float iou = iou_raw(gx, gy, gw, gh, pb);
    float cst = -(wv + sl) - 3.0f * __logf(iou + 1e-8f);
    if (!((am >> g) & 1u)) cst += 100000.0f;
    cost_tbl[row + ci] = cst;
    iou_tbl[row + ci]  = iou;
  }
}

// ---------- kB: per (b,g) streaming row + dyn_k top-k selection ----------
__global__ __launch_bounds__(256) void kB(const float* __restrict__ cost_tbl,
                                          const float* __restrict__ iou_tbl,
                                          const int* __restrict__ n_fg,
                                          unsigned int* __restrict__ match_c) {
  __shared__ float s_cost[NAP];   // 33 KB (only n used)
  __shared__ float s_wt[4 * 10];
  __shared__ float s_v[4];
  __shared__ int   s_i[4];
  __shared__ int   s_k;

  int g = blockIdx.x, b = blockIdx.y, tid = threadIdx.x;
  int lane = tid & 63, wid = tid >> 6;
  int n = n_fg[b];
  size_t bo = (size_t)b * NAP;
  const float* __restrict__ cg = cost_tbl + ((size_t)b * NG + g) * NAP;
  const float* __restrict__ ig = iou_tbl  + ((size_t)b * NG + g) * NAP;

  float t10[10];
#pragma unroll
  for (int j = 0; j < 10; ++j) t10[j] = 0.0f;

  for (int ci = tid; ci < n; ci += 256) {
    float iou = ig[ci];
    float cst = cg[ci];
    if (iou > t10[9]) {
      t10[9] = iou;
#pragma unroll
      for (int q = 9; q > 0; --q) {
        if (t10[q] > t10[q - 1]) { float t = t10[q]; t10[q] = t10[q - 1]; t10[q - 1] = t; }
        else break;
      }
    }
    s_cost[ci] = cst;
  }

  // per-wave top-10 extraction (regs+shuffles, no syncs), then 4-list merge
  for (int r = 0; r < 10; ++r) {
    float v = t10[0];
    float bv = v;
#pragma unroll
    for (int off = 32; off; off >>= 1) bv = fmaxf(bv, __shfl_down(bv, off, 64));
    bv = __shfl(bv, 0, 64);
    unsigned long long won = __ballot(v == bv);
    if (lane == __ffsll(won) - 1) {
#pragma unroll
      for (int q = 0; q < 9; ++q) t10[q] = t10[q + 1];
      t10[9] = -1.0f;
    }
    if (lane == 0) s_wt[wid * 10 + r] = bv;
  }
  __syncthreads();

  if (tid == 0) {
    int p0 = 0, p1 = 0, p2 = 0, p3 = 0;
    float s = 0.0f;
    for (int r = 0; r < 10; ++r) {
      float v0 = (p0 < 10) ? s_wt[p0]      : -2.0f;
      float v1 = (p1 < 10) ? s_wt[10 + p1] : -2.0f;
      float v2 = (p2 < 10) ? s_wt[20 + p2] : -2.0f;
      float v3 = (p3 < 10) ? s_wt[30 + p3] : -2.0f;
      float m = fmaxf(fmaxf(v0, v1), fmaxf(v2, v3));
      s += m;
      if (m == v0) ++p0; else if (m == v1) ++p1; else if (m == v2) ++p2; else ++p3;
    }
    int k = (int)s;                 // truncation matches astype(int32)
    if (k < 1) k = 1;
    s_k = k;
  }
  __syncthreads();
  int k = s_k;

  // extract k smallest among candidates (all compacted entries are fg_cand)
  for (int it = 0; it < k; ++it) {
    float bv = 3.4e38f; int bi = NAP;
    for (int ci = tid; ci < n; ci += 256) {
      float v = s_cost[ci];
      if (v < bv || (v == bv && ci < bi)) { bv = v; bi = ci; }
    }
    block_argmin(bv, bi, s_v, s_i, tid);
    if (bv >= 1e8f) break;          // unreachable safety (costs <= ~1.1e5)
    if (tid == 0) {
      atomicOr(&match_c[bo + bi], 1u << g);
      s_cost[bi] = 3.4e38f;
    }
    __syncthreads();
  }
}

// ---------- kCD: finalize matched anchors + last-block scalar epilogue ----------
__global__ __launch_bounds__(256) void kCD(const float* __restrict__ p8,
                                           const float* __restrict__ p16,
                                           const float* __restrict__ p32,
                                           const float* __restrict__ labels,
                                           const float4* __restrict__ bbox_c,
                                           const float* __restrict__ sb_c,
                                           const float* __restrict__ cost_tbl,
                                           const float* __restrict__ iou_tbl,
                                           const int* __restrict__ fg_list,
                                           const int* __restrict__ n_fg,
                                           const unsigned int* __restrict__ match_c,
                                           const float* __restrict__ blk_obj,
                                           float* __restrict__ accum,
                                           int* __restrict__ done_cnt,
                                           float* __restrict__ out) {
  __shared__ float s_gt[NG * 5];
  __shared__ float s_red[16];
  __shared__ int s_last;
  int b = blockIdx.y, tid = threadIdx.x;
  if (tid < NG * 5) s_gt[tid] = labels[(size_t)b * NG * 5 + tid];
  __syncthreads();

  int n = n_fg[b];
  size_t bo = (size_t)b * NAP;
  float li = 0.0f, oe = 0.0f, lc = 0.0f, nf = 0.0f;

  for (int ci = blockIdx.x * 256 + tid; ci < n; ci += KC_BLKS * 256) {
    unsigned int m = match_c[bo + ci];
    if (m == 0u) continue;
    int mg;
    if (m & (m - 1)) {
      // multi-matched: argmin over ALL g of precomputed cost (first-min tie-break)
      float bestc = 3.4e38f; mg = 0;
#pragma unroll 4
      for (int g = 0; g < NG; ++g) {
        float cst = cost_tbl[((size_t)b * NG + g) * NAP + ci];
        if (cst < bestc) { bestc = cst; mg = g; }
      }
    } else {
      mg = __ffs(m) - 1;
    }
    int a = fg_list[bo + ci];
    const float* base; int hw, HW, xg, yg; float fs;
    anchor_info(a, p8, p16, p32, b, base, hw, HW, xg, yg, fs);
    float4 pb = bbox_c[bo + ci];
    float gx = s_gt[mg * 5], gy = s_gt[mg * 5 + 1];
    float gw = s_gt[mg * 5 + 2], gh = s_gt[mg * 5 + 3];
    int cg = (int)s_gt[mg * 5 + 4];
    float piou = iou_tbl[((size_t)b * NG + mg) * NAP + ci];
    li += giou_loss(pb, gx, gy, gw, gh);
    float xcls = base[(size_t)(5 + cg) * HW + hw];
    lc += sb_c[bo + ci] - xcls * piou;   // bce(x,t) = bce(x,0) - x*t
    oe += base[4 * HW + hw];             // obj logit: bce(x,1) = bce(x,0) - x
    nf += 1.0f;
  }

  float vals[4] = {li, oe, lc, nf};
#pragma unroll
  for (int q = 0; q < 4; ++q) {
#pragma unroll
    for (int off = 32; off; off >>= 1) vals[q] += __shfl_down(vals[q], off, 64);
  }
  if ((tid & 63) == 0) {
    int wid = tid >> 6;
    s_red[wid * 4 + 0] = vals[0];
    s_red[wid * 4 + 1] = vals[1];
    s_red[wid * 4 + 2] = vals[2];
    s_red[wid * 4 + 3] = vals[3];
  }
  __syncthreads();
  if (tid < 4) {
    const int slot[4] = {0, 2, 3, 4};
    float s = s_red[tid] + s_red[4 + tid] + s_red[8 + tid] + s_red[12 + tid];
    atomicAdd(&accum[slot[tid]], s);
  }

  // done-ticket: last block computes the scalar output
  if (tid == 0) {
    __threadfence();
    int old = atomicAdd(done_cnt, 1);
    s_last = (old == KC_BLKS * NB - 1) ? 1 : 0;
  }
  __syncthreads();
  if (s_last) {
    float s = 0.0f;
    for (int i = tid; i < NB * NBLK; i += 256) s += blk_obj[i];  // obj-BCE base
#pragma unroll
    for (int off = 32; off; off >>= 1) s += __shfl_down(s, off, 64);
    if ((tid & 63) == 0) s_red[tid >> 6] = s;
    __syncthreads();
    if (tid == 0) {
      float obj_base = s_red[0] + s_red[1] + s_red[2] + s_red[3];
      float loss_iou = atomicAdd(&accum[0], 0.0f);   // coherent read-backs
      float oex      = atomicAdd(&accum[2], 0.0f);
      float loss_cls = atomicAdd(&accum[3], 0.0f);
      float num_fg   = atomicAdd(&accum[4], 0.0f);
      float loss_obj = obj_base - oex;
      out[0] = (5.0f * loss_iou + loss_obj + loss_cls) / fmaxf(num_fg, 1.0f);
    }
  }
}

// ---------- launch ----------
extern "C" void kernel_launch(void* const* d_in, const int* in_sizes, int n_in,
                              void* d_out, int out_size, void* d_ws, size_t ws_size,
                              hipStream_t stream) {
  const float* p8     = (const float*)d_in[0];
  const float* p16    = (const float*)d_in[1];
  const float* p32    = (const float*)d_in[2];
  const float* labels = (const float*)d_in[3];
  float* out = (float*)d_out;

  const size_t BAP = (size_t)NB * NAP;     // 270336
  char* w = (char*)d_ws;
  float4*       bbox_c   = (float4*)w;                             // 4.3 MB, 16B-aligned
  float*        cost_tbl = (float*)(w + BAP * 16);                 // NB*NG*NAP*4 = 21.6 MB
  float*        iou_tbl  = cost_tbl + (size_t)NB * NG * NAP;       // 21.6 MB
  char*         w2       = (char*)(iou_tbl + (size_t)NB * NG * NAP);
  int*          fg_list  = (int*)(w2);
  unsigned int* match_c  = (unsigned int*)(w2 + BAP * 4);
  float*        sb_c     = (float*)(w2 + BAP * 8);
  float*        sl_c     = (float*)(w2 + BAP * 12);
  float*        lso_c    = (float*)(w2 + BAP * 16);
  unsigned int* am_c     = (unsigned int*)(w2 + BAP * 20);
  char*         w3       = w2 + BAP * 24;
  // zeroed region: n_fg_cnt (NB ints) + accum (8 f) + done_cnt (1 int) = 256 B
  int*          n_fg     = (int*)w3;
  float*        accum    = (float*)(w3 + 128);
  int*          done_cnt = (int*)(w3 + 160);
  float*        blk_obj  = (float*)(w3 + 256);                     // NB*NBLK floats

  hipMemsetAsync(w3, 0, 256, stream);

  k1<<<dim3(NBLK, NB), dim3(256), 0, stream>>>(p8, p16, p32, labels, n_fg, fg_list, am_c,
                                               bbox_c, lso_c, match_c, blk_obj);
  k2<<<dim3(24, NB), dim3(256), 0, stream>>>(p8, p16, p32, fg_list, n_fg, lso_c, sl_c, sb_c);
  k3<<<dim3(12, NG, NB), dim3(256), 0, stream>>>(p8, p16, p32, labels, fg_list, n_fg, lso_c,
                                                 sl_c, bbox_c, am_c, cost_tbl, iou_tbl);
  kB<<<dim3(NG, NB), dim3(256), 0, stream>>>(cost_tbl, iou_tbl, n_fg, match_c);
  kCD<<<dim3(KC_BLKS, NB), dim3(256), 0, stream>>>(p8, p16, p32, labels, bbox_c, sb_c,
                                                   cost_tbl, iou_tbl, fg_list, n_fg,
                                                   match_c, blk_obj, accum, done_cnt, out);
}

// Round 9
// 173.167 us; speedup vs baseline: 2.6837x; 1.0013x over previous
//
#include <hip/hip_runtime.h>
#include <cstdint>
#include <cstddef>

#define NA 8400   // anchors per image: 80*80 + 40*40 + 20*20
#define NAP 8448  // padded stride (33*256)
#define NB 32     // batch
#define NG 20     // ground truths per image
#define NCL 80    // classes
#define NBLK 33   // 256-thread blocks per image

// ---------- fast math ----------
__device__ __forceinline__ float frcp(float x) { return __builtin_amdgcn_rcpf(x); }
__device__ __forceinline__ float bce0(float x) {
  return fmaxf(x, 0.0f) + __logf(1.0f + __expf(-fabsf(x)));
}

__device__ __forceinline__ void anchor_info(int a, const float* p8, const float* p16,
                                            const float* p32, int b, const float*& base,
                                            int& hw, int& HW, int& xg, int& yg, float& fs) {
  if (a < 6400)      { hw = a;        HW = 6400; xg = hw % 80; yg = hw / 80; fs = 8.f;
                       base = p8  + (size_t)b * 85 * 6400; }
  else if (a < 8000) { hw = a - 6400; HW = 1600; xg = hw % 40; yg = hw / 40; fs = 16.f;
                       base = p16 + (size_t)b * 85 * 1600; }
  else               { hw = a - 8000; HW = 400;  xg = hw % 20; yg = hw / 20; fs = 32.f;
                       base = p32 + (size_t)b * 85 * 400; }
}

__device__ __forceinline__ float iou_raw(float gx, float gy, float gw, float gh, float4 p) {
  float gtlx = gx - gw * 0.5f, gtly = gy - gh * 0.5f;
  float gbrx = gx + gw * 0.5f, gbry = gy + gh * 0.5f;
  float ptlx = p.x - p.z * 0.5f, ptly = p.y - p.w * 0.5f;
  float pbrx = p.x + p.z * 0.5f, pbry = p.y + p.w * 0.5f;
  float tlx = fmaxf(gtlx, ptlx), tly = fmaxf(gtly, ptly);
  float brx = fminf(gbrx, pbrx), bry = fminf(gbry, pbry);
  float inter = ((tlx < brx) && (tly < bry)) ? (brx - tlx) * (bry - tly) : 0.0f;
  float ag = gw * gh, ap = p.z * p.w;
  return inter * frcp(ag + ap - inter + 1e-16f);
}

__device__ __forceinline__ float giou_loss(float4 bb, float gx, float gy, float gw, float gh) {
  float btlx = bb.x - bb.z * 0.5f, btly = bb.y - bb.w * 0.5f;
  float bbrx = bb.x + bb.z * 0.5f, bbry = bb.y + bb.w * 0.5f;
  float gtlx = gx - gw * 0.5f, gtly = gy - gh * 0.5f;
  float gbrx = gx + gw * 0.5f, gbry = gy + gh * 0.5f;
  float tlx = fmaxf(btlx, gtlx), tly = fmaxf(btly, gtly);
  float brx = fminf(bbrx, gbrx), bry = fminf(bbry, gbry);
  float area_b = bb.z * bb.w, area_g = gw * gh;
  float inter = ((tlx < brx) && (tly < bry)) ? (brx - tlx) * (bry - tly) : 0.0f;
  float uni = area_b + area_g - inter;
  float iou = inter / (uni + 1e-16f);
  float ctlx = fminf(btlx, gtlx), ctly = fminf(btly, gtly);
  float cbrx = fmaxf(bbrx, gbrx), cbry = fmaxf(bbry, gbry);
  float area_c = fmaxf((cbrx - ctlx) * (cbry - ctly), 1e-16f);
  float giou = iou - (area_c - uni) / area_c;
  giou = fminf(fmaxf(giou, -1.0f), 1.0f);
  return 1.0f - giou;
}

__device__ __forceinline__ void block_argmin(float& v, int& i, volatile float* s_v,
                                             volatile int* s_i, int tid) {
#pragma unroll
  for (int off = 32; off; off >>= 1) {
    float ov = __shfl_down(v, off, 64);
    int   oi = __shfl_down(i, off, 64);
    if (ov < v || (ov == v && oi < i)) { v = ov; i = oi; }
  }
  if ((tid & 63) == 0) { s_v[tid >> 6] = v; s_i[tid >> 6] = i; }
  __syncthreads();
  v = s_v[0]; i = s_i[0];
#pragma unroll
  for (int w = 1; w < 4; ++w) {
    float ov = s_v[w]; int oi = s_i[w];
    if (ov < v || (ov == v && oi < i)) { v = ov; i = oi; }
  }
}

// ---------- k1: geometry + compaction + bbox/lso decode + obj-BCE ----------
__global__ __launch_bounds__(256) void k1(const float* __restrict__ p8,
                                          const float* __restrict__ p16,
                                          const float* __restrict__ p32,
                                          const float* __restrict__ labels,
                                          int* __restrict__ n_fg_cnt,
                                          int* __restrict__ fg_list,
                                          unsigned int* __restrict__ am_c,
                                          float4* __restrict__ bbox_c,
                                          float* __restrict__ lso_c,
                                          unsigned int* __restrict__ match_c,
                                          float* __restrict__ blk_obj) {
  __shared__ float s_gt[NG * 4];
  __shared__ unsigned int s_wcnt[4];
  __shared__ float s_part[4];
  __shared__ unsigned int s_base;
  int blk = blockIdx.x, b = blockIdx.y, tid = threadIdx.x, lane = tid & 63, wid = tid >> 6;

  if (tid < NG) {
    s_gt[tid * 4 + 0] = labels[((size_t)b * NG + tid) * 5 + 0];
    s_gt[tid * 4 + 1] = labels[((size_t)b * NG + tid) * 5 + 1];
    s_gt[tid * 4 + 2] = labels[((size_t)b * NG + tid) * 5 + 2];
    s_gt[tid * 4 + 3] = labels[((size_t)b * NG + tid) * 5 + 3];
  }
  __syncthreads();

  int a = blk * 256 + tid;
  match_c[(size_t)b * NAP + a] = 0u;     // NBLK*256 == NAP: full coverage

  bool fg = false;
  unsigned int msk = 0u;
  float bce_obj = 0.0f, obj = 0.0f;
  const float* base = nullptr; int hw = 0, HW = 0, xg = 0, yg = 0; float fs = 8.f;
  if (a < NA) {
    anchor_info(a, p8, p16, p32, b, base, hw, HW, xg, yg, fs);
    obj = base[4 * HW + hw];             // coalesced obj-plane stream
    bce_obj = bce0(obj);
    float xc = ((float)xg + 0.5f) * fs;
    float yc = ((float)yg + 0.5f) * fs;
    float r = 2.5f * fs;
#pragma unroll
    for (int g = 0; g < NG; ++g) {
      float gx = s_gt[g * 4 + 0], gy = s_gt[g * 4 + 1];
      float gw = s_gt[g * 4 + 2], gh = s_gt[g * 4 + 3];
      bool inb = (xc > gx - 0.5f * gw) && (xc < gx + 0.5f * gw) &&
                 (yc > gy - 0.5f * gh) && (yc < gy + 0.5f * gh);
      bool inc = (xc > gx - r) && (xc < gx + r) && (yc > gy - r) && (yc < gy + r);
      fg = fg || inb || inc;
      if (inb && inc) msk |= (1u << g);
    }
  }

  unsigned long long bm = __ballot(fg);
#pragma unroll
  for (int off = 32; off; off >>= 1) bce_obj += __shfl_down(bce_obj, off, 64);
  if (lane == 0) { s_wcnt[wid] = (unsigned int)__popcll(bm); s_part[wid] = bce_obj; }
  __syncthreads();
  if (tid == 0) {
    unsigned int cnt = s_wcnt[0] + s_wcnt[1] + s_wcnt[2] + s_wcnt[3];
    s_base = cnt ? (unsigned int)atomicAdd(&n_fg_cnt[b], (int)cnt) : 0u;
    blk_obj[b * NBLK + blk] = s_part[0] + s_part[1] + s_part[2] + s_part[3];
  }
  __syncthreads();

  if (!fg) return;
  unsigned int pos = s_base;
  for (int w = 0; w < wid; ++w) pos += s_wcnt[w];
  pos += (unsigned int)__popcll(bm & ((1ull << lane) - 1ull));
  size_t bo = (size_t)b * NAP;
  int ci = (int)pos;
  fg_list[bo + ci] = a;
  am_c[bo + ci] = msk;

  float v0 = base[hw];
  float v1 = base[HW + hw];
  float v2 = base[2 * HW + hw];
  float v3 = base[3 * HW + hw];
  bbox_c[bo + ci] = make_float4((v0 + (float)xg) * fs, (v1 + (float)yg) * fs,
                                __expf(v2) * fs, __expf(v3) * fs);
  // log(sigmoid(obj)) = min(obj,0) - log(1+exp(-|obj|))
  float uo = __logf(1.0f + __expf(-fabsf(obj)));
  lso_c[bo + ci] = fminf(obj, 0.0f) - uo;
}

// ---------- k23: class sums (8 thr/anchor) + cost/iou tables, fused ----------
// Tile = 32 anchors. Phase A: part p sums classes [10p,10p+10) -> LDS reduce -> sl,sb.
// Phase B: part p computes cost/iou for g in {p, p+8, p+16} for its anchor.
__global__ __launch_bounds__(256) void k23(const float* __restrict__ p8,
                                           const float* __restrict__ p16,
                                           const float* __restrict__ p32,
                                           const float* __restrict__ labels,
                                           const int* __restrict__ fg_list,
                                           const int* __restrict__ n_fg,
                                           const float* __restrict__ lso_c,
                                           const unsigned int* __restrict__ am_c,
                                           const float4* __restrict__ bbox_c,
                                           float* __restrict__ sb_c,
                                           float* __restrict__ cost_tbl,
                                           float* __restrict__ iou_tbl) {
  __shared__ float s_gt[NG * 4];
  __shared__ int   s_gcls[NG];
  __shared__ float s_sl[8][33];
  __shared__ float s_sb[8][33];
  __shared__ float s_slr[32];
  int b = blockIdx.y, tid = threadIdx.x;
  int part = tid >> 5, cl = tid & 31;

  if (tid < NG) {
    s_gt[tid * 4 + 0] = labels[((size_t)b * NG + tid) * 5 + 0];
    s_gt[tid * 4 + 1] = labels[((size_t)b * NG + tid) * 5 + 1];
    s_gt[tid * 4 + 2] = labels[((size_t)b * NG + tid) * 5 + 2];
    s_gt[tid * 4 + 3] = labels[((size_t)b * NG + tid) * 5 + 3];
    s_gcls[tid] = (int)labels[((size_t)b * NG + tid) * 5 + 4];
  }
  __syncthreads();

  int n = n_fg[b];
  size_t bo = (size_t)b * NAP;

  for (int base_ci = blockIdx.x * 32; base_ci < n; base_ci += gridDim.x * 32) {
    int ci = base_ci + cl;
    bool act = ci < n;
    const float* base = nullptr; int hw = 0, HW = 0, xg, yg; float fs;
    float lso = 0.0f, sl = 0.0f, sb = 0.0f;
    if (act) {
      int a = fg_list[bo + ci];
      lso = lso_c[bo + ci];
      anchor_info(a, p8, p16, p32, b, base, hw, HW, xg, yg, fs);
      const float* cb = base + (size_t)(5 + part * 10) * HW + hw;
      float xs[10];
#pragma unroll
      for (int j = 0; j < 10; ++j) xs[j] = cb[(size_t)j * HW];
#pragma unroll
      for (int j = 0; j < 10; ++j) {
        float x = xs[j];
        float u = __logf(1.0f + __expf(-fabsf(x)));
        sb += fmaxf(x, 0.0f) + u;                 // bce(x,0)
        float lsx = fminf(x, 0.0f) - u;           // log(sigmoid(x))
        float lpr = 0.5f * (lsx + lso);           // log p
        float p   = __expf(lpr);
        sl += fmaxf(__logf(1.0f - p), -100.0f);
      }
    }
    s_sl[part][cl] = sl;
    s_sb[part][cl] = sb;
    __syncthreads();
    if (tid < 32) {
      float tsl = 0.0f, tsb = 0.0f;
#pragma unroll
      for (int q = 0; q < 8; ++q) { tsl += s_sl[q][tid]; tsb += s_sb[q][tid]; }
      s_slr[tid] = tsl;
      if (base_ci + tid < n) sb_c[bo + base_ci + tid] = tsb;
    }
    __syncthreads();
    if (act) {
      float slr = s_slr[cl];
      unsigned int am = am_c[bo + ci];
      float4 pb = bbox_c[bo + ci];
#pragma unroll
      for (int gg = 0; gg < 3; ++gg) {
        int g = part + (gg << 3);
        if (g < NG) {
          int cg = s_gcls[g];
          float x = base[(size_t)(5 + cg) * HW + hw];
          float u = __logf(1.0f + __expf(-fabsf(x)));
          float lsx = fminf(x, 0.0f) - u;
          float lpr = 0.5f * (lsx + lso);
          float p   = __expf(lpr);
          float l1p = fmaxf(__logf(1.0f - p), -100.0f);
          float wv  = fmaxf(lpr, -100.0f) - l1p;  // lp - l1p
          float iou = iou_raw(s_gt[g * 4 + 0], s_gt[g * 4 + 1],
                              s_gt[g * 4 + 2], s_gt[g * 4 + 3], pb);
          float cst = -(wv + slr) - 3.0f * __logf(iou + 1e-8f);
          if (!((am >> g) & 1u)) cst += 100000.0f;
          size_t row = ((size_t)b * NG + g) * NAP;
          cost_tbl[row + ci] = cst;
          iou_tbl[row + ci]  = iou;
        }
      }
    }
    __syncthreads();   // protect s_sl/s_sb/s_slr reuse next tile
  }
}

// ---------- kBCD: per-(b,g) top-k + per-image finalize ticket + final scalar ----------
__global__ __launch_bounds__(256) void kBCD(const float* __restrict__ p8,
                                            const float* __restrict__ p16,
                                            const float* __restrict__ p32,
                                            const float* __restrict__ labels,
                                            const float* __restrict__ cost_tbl,
                                            const float* __restrict__ iou_tbl,
                                            const int* __restrict__ n_fg,
                                            unsigned int* __restrict__ match_c,
                                            const int* __restrict__ fg_list,
                                            const float4* __restrict__ bbox_c,
                                            const float* __restrict__ sb_c,
                                            const float* __restrict__ blk_obj,
                                            float* __restrict__ accum,
                                            int* __restrict__ done_g,
                                            int* __restrict__ done_img,
                                            float* __restrict__ out) {
  __shared__ float s_cost[NAP];   // 33 KB
  __shared__ float s_wt[4 * 10];
  __shared__ float s_v[4];
  __shared__ int   s_i[4];
  __shared__ int   s_k;
  __shared__ int   s_flag;
  __shared__ float s_gt[NG * 5];
  __shared__ float s_red[16];

  int g = blockIdx.x, b = blockIdx.y, tid = threadIdx.x;
  int lane = tid & 63, wid = tid >> 6;
  int n = n_fg[b];
  size_t bo = (size_t)b * NAP;
  const float* __restrict__ cg = cost_tbl + ((size_t)b * NG + g) * NAP;
  const float* __restrict__ ig = iou_tbl  + ((size_t)b * NG + g) * NAP;

  float t10[10];
#pragma unroll
  for (int j = 0; j < 10; ++j) t10[j] = 0.0f;

  for (int ci = tid; ci < n; ci += 256) {
    float iou = ig[ci];
    float cst = cg[ci];
    if (iou > t10[9]) {
      t10[9] = iou;
#pragma unroll
      for (int q = 9; q > 0; --q) {
        if (t10[q] > t10[q - 1]) { float t = t10[q]; t10[q] = t10[q - 1]; t10[q - 1] = t; }
        else break;
      }
    }
    s_cost[ci] = cst;
  }

  // per-wave top-10 extraction (regs+shuffles, no syncs), then 4-list merge
  for (int r = 0; r < 10; ++r) {
    float v = t10[0];
    float bv = v;
#pragma unroll
    for (int off = 32; off; off >>= 1) bv = fmaxf(bv, __shfl_down(bv, off, 64));
    bv = __shfl(bv, 0, 64);
    unsigned long long won = __ballot(v == bv);
    if (lane == __ffsll(won) - 1) {
#pragma unroll
      for (int q = 0; q < 9; ++q) t10[q] = t10[q + 1];
      t10[9] = -1.0f;
    }
    if (lane == 0) s_wt[wid * 10 + r] = bv;
  }
  __syncthreads();

  if (tid == 0) {
    int p0 = 0, p1 = 0, p2 = 0, p3 = 0;
    float s = 0.0f;
    for (int r = 0; r < 10; ++r) {
      float v0 = (p0 < 10) ? s_wt[p0]      : -2.0f;
      float v1 = (p1 < 10) ? s_wt[10 + p1] : -2.0f;
      float v2 = (p2 < 10) ? s_wt[20 + p2] : -2.0f;
      float v3 = (p3 < 10) ? s_wt[30 + p3] : -2.0f;
      float m = fmaxf(fmaxf(v0, v1), fmaxf(v2, v3));
      s += m;
      if (m == v0) ++p0; else if (m == v1) ++p1; else if (m == v2) ++p2; else ++p3;
    }
    int k = (int)s;                 // truncation matches astype(int32)
    if (k < 1) k = 1;
    s_k = k;
  }
  __syncthreads();
  int k = s_k;

  // extract k smallest among candidates
  for (int it = 0; it < k; ++it) {
    float bv = 3.4e38f; int bi = NAP;
    for (int ci = tid; ci < n; ci += 256) {
      float v = s_cost[ci];
      if (v < bv || (v == bv && ci < bi)) { bv = v; bi = ci; }
    }
    block_argmin(bv, bi, s_v, s_i, tid);
    if (bv >= 1e8f) break;          // exhausted real candidates
    if (tid == 0) {
      atomicOr(&match_c[bo + bi], 1u << g);
      s_cost[bi] = 3.4e38f;
    }
    __syncthreads();
  }

  // ---- per-image ticket: 20th row-block of image b runs the finalize scan ----
  __syncthreads();
  if (tid == 0) {
    __threadfence();
    s_flag = (atomicAdd(&done_g[b], 1) == NG - 1) ? 1 : 0;
  }
  __syncthreads();
  if (!s_flag) return;

  if (tid < NG * 5) s_gt[tid] = labels[(size_t)b * NG * 5 + tid];
  __syncthreads();

  float li = 0.0f, oe = 0.0f, lc = 0.0f, nf = 0.0f;
  for (int ci = tid; ci < n; ci += 256) {
    unsigned int m = atomicOr(&match_c[bo + ci], 0u);   // coherence-point read
    if (m == 0u) continue;
    int mg;
    if (m & (m - 1)) {
      float bestc = 3.4e38f; mg = 0;
#pragma unroll 4
      for (int gq = 0; gq < NG; ++gq) {
        float cst = cost_tbl[((size_t)b * NG + gq) * NAP + ci];
        if (cst < bestc) { bestc = cst; mg = gq; }
      }
    } else {
      mg = __ffs(m) - 1;
    }
    int a = fg_list[bo + ci];
    const float* base; int hw, HW, xg, yg; float fs;
    anchor_info(a, p8, p16, p32, b, base, hw, HW, xg, yg, fs);
    float4 pb = bbox_c[bo + ci];
    float gx = s_gt[mg * 5], gy = s_gt[mg * 5 + 1];
    float gw = s_gt[mg * 5 + 2], gh = s_gt[mg * 5 + 3];
    int cgq = (int)s_gt[mg * 5 + 4];
    float piou = iou_tbl[((size_t)b * NG + mg) * NAP + ci];
    li += giou_loss(pb, gx, gy, gw, gh);
    float xcls = base[(size_t)(5 + cgq) * HW + hw];
    lc += sb_c[bo + ci] - xcls * piou;   // bce(x,t) = bce(x,0) - x*t
    oe += base[4 * HW + hw];             // obj logit: bce(x,1) = bce(x,0) - x
    nf += 1.0f;
  }

  float vals[4] = {li, oe, lc, nf};
#pragma unroll
  for (int q = 0; q < 4; ++q) {
#pragma unroll
    for (int off = 32; off; off >>= 1) vals[q] += __shfl_down(vals[q], off, 64);
  }
  if ((tid & 63) == 0) {
    int w = tid >> 6;
    s_red[w * 4 + 0] = vals[0];
    s_red[w * 4 + 1] = vals[1];
    s_red[w * 4 + 2] = vals[2];
    s_red[w * 4 + 3] = vals[3];
  }
  __syncthreads();
  if (tid < 4) {
    const int slot[4] = {0, 2, 3, 4};
    float s = s_red[tid] + s_red[4 + tid] + s_red[8 + tid] + s_red[12 + tid];
    atomicAdd(&accum[slot[tid]], s);
  }

  // ---- final ticket: last image's finalize block emits the scalar ----
  if (tid == 0) {
    __threadfence();
    s_flag = (atomicAdd(done_img, 1) == NB - 1) ? 1 : 0;
  }
  __syncthreads();
  if (!s_flag) return;

  float s = 0.0f;
  for (int i = tid; i < NB * NBLK; i += 256) s += blk_obj[i];  // obj-BCE base
#pragma unroll
  for (int off = 32; off; off >>= 1) s += __shfl_down(s, off, 64);
  if ((tid & 63) == 0) s_red[tid >> 6] = s;
  __syncthreads();
  if (tid == 0) {
    float obj_base = s_red[0] + s_red[1] + s_red[2] + s_red[3];
    float loss_iou = atomicAdd(&accum[0], 0.0f);   // coherent read-backs
    float oex      = atomicAdd(&accum[2], 0.0f);
    float loss_cls = atomicAdd(&accum[3], 0.0f);
    float num_fg   = atomicAdd(&accum[4], 0.0f);
    float loss_obj = obj_base - oex;
    out[0] = (5.0f * loss_iou + loss_obj + loss_cls) / fmaxf(num_fg, 1.0f);
  }
}

// ---------- launch ----------
extern "C" void kernel_launch(void* const* d_in, const int* in_sizes, int n_in,
                              void* d_out, int out_size, void* d_ws, size_t ws_size,
                              hipStream_t stream) {
  const float* p8     = (const float*)d_in[0];
  const float* p16    = (const float*)d_in[1];
  const float* p32    = (const float*)d_in[2];
  const float* labels = (const float*)d_in[3];
  float* out = (float*)d_out;

  const size_t BAP = (size_t)NB * NAP;     // 270336
  char* w = (char*)d_ws;
  float4*       bbox_c   = (float4*)w;                             // 4.3 MB, 16B-aligned
  float*        cost_tbl = (float*)(w + BAP * 16);                 // NB*NG*NAP*4 = 21.6 MB
  float*        iou_tbl  = cost_tbl + (size_t)NB * NG * NAP;       // 21.6 MB
  char*         w2       = (char*)(iou_tbl + (size_t)NB * NG * NAP);
  int*          fg_list  = (int*)(w2);
  unsigned int* match_c  = (unsigned int*)(w2 + BAP * 4);
  float*        sb_c     = (float*)(w2 + BAP * 8);
  float*        lso_c    = (float*)(w2 + BAP * 12);
  unsigned int* am_c     = (unsigned int*)(w2 + BAP * 16);
  char*         w3       = w2 + BAP * 20;
  // zeroed region (512 B): n_fg(32i)@0, accum(8f)@128, done_g(32i)@256, done_img@384
  int*          n_fg     = (int*)w3;
  float*        accum    = (float*)(w3 + 128);
  int*          done_g   = (int*)(w3 + 256);
  int*          done_img = (int*)(w3 + 384);
  float*        blk_obj  = (float*)(w3 + 512);                     // NB*NBLK floats

  hipMemsetAsync(w3, 0, 512, stream);

  k1<<<dim3(NBLK, NB), dim3(256), 0, stream>>>(p8, p16, p32, labels, n_fg, fg_list, am_c,
                                               bbox_c, lso_c, match_c, blk_obj);
  k23<<<dim3(NBLK, NB), dim3(256), 0, stream>>>(p8, p16, p32, labels, fg_list, n_fg, lso_c,
                                                am_c, bbox_c, sb_c, cost_tbl, iou_tbl);
  kBCD<<<dim3(NG, NB), dim3(256), 0, stream>>>(p8, p16, p32, labels, cost_tbl, iou_tbl,
                                               n_fg, match_c, fg_list, bbox_c, sb_c,
                                               blk_obj, accum, done_g, done_img, out);
}